// Round 12
// baseline (733.073 us; speedup 1.0000x reference)
//
#include <hip/hip_runtime.h>
#include <cstdint>
#include <cstddef>

#define D_MODEL 768
#define D_SAE   24576
#define KSEL    32
#define NBATCH  4096

typedef _Float16 f16x8 __attribute__((ext_vector_type(8)));
typedef _Float16 f16x4 __attribute__((ext_vector_type(4)));
typedef float    f32x4 __attribute__((ext_vector_type(4)));

// f16 element counts of the split matrices (stored in the z_sparse region as scratch)
#define W_ELEMS  ((size_t)D_MODEL * D_SAE)   // 18,874,368
#define X_ELEMS  ((size_t)NBATCH * D_MODEL)  // 3,145,728

#define TCAND 2.4f      // candidate threshold (v32 per row is ~2.8-3.3)
#define CAP_G 1024      // per-row global candidate capacity
#define BCAP  160       // boundary-recompute capacity per row
#define DELTA 0.06f     // boundary half-width (~40 sigma of pairwise approx err)
#define VGATE 0.05f     // skip boundary repair when the cut is ~0 (harmless flips)

// ---------------------------------------------------------------------------
// split_x: X[4096][768] f32 -> Xh,Xl' blocked f16  (xl' = (x - xh)*2^11)
// Tile = [128 m][64 k] f16 (16 KiB); element index within tile =
//   m*64 + ((k>>3) ^ (m&7))*8 + (k&7)   (XOR chunk swizzle baked in)
// ---------------------------------------------------------------------------
__global__ void split_x(const float* __restrict__ X,
                        _Float16* __restrict__ Xh, _Float16* __restrict__ Xl)
{
  const int tile = blockIdx.x;
  const int mb = tile / 12, kb = tile % 12;
  const int t = threadIdx.x;
#pragma unroll
  for (int r = 0; r < 8; ++r) {
    const int flat4 = r * 256 + t;          // 0..2047
    const int m  = flat4 >> 4;              // 0..127
    const int k4 = (flat4 & 15) << 2;       // 0,4,...,60
    const float4 v = *reinterpret_cast<const float4*>(
        &X[(size_t)(mb * 128 + m) * D_MODEL + kb * 64 + k4]);
    const float xx[4] = {v.x, v.y, v.z, v.w};
    f16x4 h, l;
#pragma unroll
    for (int c = 0; c < 4; ++c) {
      const _Float16 hh = (_Float16)xx[c];
      h[c] = hh;
      l[c] = (_Float16)((xx[c] - (float)hh) * 2048.0f);
    }
    const size_t base = ((size_t)(mb * 12 + kb)) * 8192 +
                        m * 64 + (((k4 >> 3) ^ (m & 7)) << 3) + (k4 & 7);
    *reinterpret_cast<f16x4*>(&Xh[base]) = h;
    *reinterpret_cast<f16x4*>(&Xl[base]) = l;
  }
}

// ---------------------------------------------------------------------------
// split_w: W[768][24576] f32 -> Wh,Wl' blocked-TRANSPOSED f16 tiles [n][k]
// ---------------------------------------------------------------------------
__global__ void split_w(const float* __restrict__ W,
                        _Float16* __restrict__ Wh, _Float16* __restrict__ Wl)
{
  __shared__ float Ws[64][129];
  const int tile = blockIdx.x;
  const int nb = tile / 12, kb = tile % 12;
  const int t = threadIdx.x;
#pragma unroll
  for (int r = 0; r < 8; ++r) {
    const int flat4 = r * 256 + t;
    const int k  = flat4 >> 5;              // 0..63
    const int n4 = (flat4 & 31) << 2;       // 0..124
    const float4 v = *reinterpret_cast<const float4*>(
        &W[(size_t)(kb * 64 + k) * D_SAE + nb * 128 + n4]);
    Ws[k][n4 + 0] = v.x; Ws[k][n4 + 1] = v.y; Ws[k][n4 + 2] = v.z; Ws[k][n4 + 3] = v.w;
  }
  __syncthreads();
#pragma unroll
  for (int r = 0; r < 4; ++r) {
    const int u = r * 256 + t;              // 0..1023
    const int n = u >> 3;                   // 0..127
    const int c = u & 7;                    // k-octet
    f16x8 h, l;
#pragma unroll
    for (int i = 0; i < 8; ++i) {
      const float w = Ws[c * 8 + i][n];
      const _Float16 hh = (_Float16)w;
      h[i] = hh;
      l[i] = (_Float16)((w - (float)hh) * 2048.0f);
    }
    const size_t base = ((size_t)(nb * 12 + kb)) * 8192 + n * 64 + ((c ^ (n & 7)) << 3);
    *reinterpret_cast<f16x8*>(&Wh[base]) = h;
    *reinterpret_cast<f16x8*>(&Wl[base]) = l;
  }
}

// ---------------------------------------------------------------------------
__global__ void zero_cnt(int* cnt) { cnt[blockIdx.x * 256 + threadIdx.x] = 0; }

// zero_zs: stream 403 MB of zeros into Zs (non-temporal, grid-stride)
__global__ __launch_bounds__(256) void zero_zs(float* __restrict__ Zs)
{
  const size_t n4 = (size_t)NBATCH * D_SAE / 4;
  const f32x4 z = {0.0f, 0.0f, 0.0f, 0.0f};
  const size_t stride = (size_t)gridDim.x * 256;
  f32x4* p = reinterpret_cast<f32x4*>(Zs);
  for (size_t i = (size_t)blockIdx.x * 256 + threadIdx.x; i < n4; i += stride)
    __builtin_nontemporal_store(z, p + i);
}

// scatter_k: write the 32 selected values into the pre-zeroed Zs
__global__ __launch_bounds__(256) void scatter_k(const uint2* __restrict__ selbuf,
                                                 float* __restrict__ Zs)
{
  const int i = blockIdx.x * 256 + threadIdx.x;   // 0..131071
  const int row = i >> 5, slot = i & 31;
  const uint2 p = selbuf[row * KSEL + slot];
  if (p.x) Zs[(size_t)row * D_SAE + p.y] = __uint_as_float(p.x);
}

// ---------------------------------------------------------------------------
__device__ __forceinline__ void gll16(void* lds, const void* g) {
  __builtin_amdgcn_global_load_lds(
      (const __attribute__((address_space(1))) unsigned int*)g,
      (__attribute__((address_space(3))) unsigned int*)lds, 16, 0, 0);
}

// ---------------------------------------------------------------------------
// gemm8: ONE-pass approx GEMM  Zp = Xh@Wh + be  on a 256x256 tile, 8 waves
// (512 thr, 2M x 4N), BK=64, double-buffered 128 KB dynamic LDS.
// Per K-tile: {vmcnt(0); s_barrier; stage next tile into buf^1 (8 gll16);
// 4 phases of ds_read + 16 MFMA (setprio-wrapped), no intra-tile barriers}.
// Staged loads get a full tile (~4 phases) to land; overwrite-safe by
// construction (issue is after the barrier retiring the target buffer).
// Epilogue: non-temporal Zp store + candidate append (> TCAND).
// ---------------------------------------------------------------------------
__global__ __launch_bounds__(512, 1) void gemm8(
    const _Float16* __restrict__ Xh, const _Float16* __restrict__ Wh,
    const float* __restrict__ be, float* __restrict__ Zp,
    uint2* __restrict__ cand, int* __restrict__ cnt)
{
  extern __shared__ char lds[];   // 131072 B: buf b at b*65536; A0,A1,B0,B1 16KB

  const int bid = blockIdx.x;
  const int wg  = (bid & 7) * 192 + (bid >> 3);   // XCD-contiguous (1536%8==0)
  const int mb  = wg & 15;                        // 16 m-tiles of 256
  const int nb  = wg >> 4;                        // 96 n-tiles of 256

  const int t = threadIdx.x, lane = t & 63, w = t >> 6;
  const int wm = w >> 2, wn = w & 3;              // 2M x 4N wave grid
  const int l15 = lane & 15, lq = lane >> 4;
  const int c0 = (lq ^ (lane & 7)) * 16;

  f32x4 acc[8][4] = {};

  const char* gA0 = (const char*)Xh + (size_t)((mb * 2 + 0) * 12) * 16384;
  const char* gA1 = (const char*)Xh + (size_t)((mb * 2 + 1) * 12) * 16384;
  const char* gB0 = (const char*)Wh + (size_t)((nb * 2 + 0) * 12) * 16384;
  const char* gB1 = (const char*)Wh + (size_t)((nb * 2 + 1) * 12) * 16384;

  const int dsto = (t & 448) * 16;       // wave-uniform base (+ lane*16 implicit)
  const int tsrc = t * 16;

  auto stage_tile = [&](int ks) {        // 8 gll16 into buf ks&1
    char* base = lds + (ks & 1) * 65536 + dsto;
    const int go = ks * 16384 + tsrc;
    gll16(base,                 gA0 + go);
    gll16(base + 8192,          gA0 + go + 8192);
    gll16(base + 16384,         gA1 + go);
    gll16(base + 16384 + 8192,  gA1 + go + 8192);
    gll16(base + 32768,         gB0 + go);
    gll16(base + 32768 + 8192,  gB0 + go + 8192);
    gll16(base + 49152,         gB1 + go);
    gll16(base + 49152 + 8192,  gB1 + go + 8192);
  };

  stage_tile(0);

  const int bcol0 = (wn & 1) * 64;       // col base within B half-tile

  for (int ks = 0; ks < 12; ++ks) {
    asm volatile("s_waitcnt vmcnt(0)" ::: "memory");   // tile ks fully in LDS
    __builtin_amdgcn_s_barrier();                      // all waves' loads done
    __builtin_amdgcn_sched_barrier(0);                 // pin: nothing hoists up
    if (ks + 1 < 12) stage_tile(ks + 1);               // into buf^1 (retired)
    const char* A = lds + (ks & 1) * 65536 + wm * 16384;
    const char* B = lds + (ks & 1) * 65536 + 32768 + (wn >> 1) * 16384;
    f16x8 a[4], b[4];
#pragma unroll
    for (int ph = 0; ph < 4; ++ph) {
      const int ih = ph & 1;                           // (0,0),(1,0),(0,1),(1,1)
      const int kk = ph >> 1;
      if (ih == 0) {
#pragma unroll
        for (int j = 0; j < 4; ++j)
          b[j] = *reinterpret_cast<const f16x8*>(
              B + (((bcol0 + j * 16 + l15) * 128 + c0) ^ (kk * 64)));
      }
#pragma unroll
      for (int i2 = 0; i2 < 4; ++i2)
        a[i2] = *reinterpret_cast<const f16x8*>(
            A + ((((ih * 4 + i2) * 16 + l15) * 128 + c0) ^ (kk * 64)));
      __builtin_amdgcn_s_setprio(1);
#pragma unroll
      for (int i2 = 0; i2 < 4; ++i2)
#pragma unroll
        for (int j = 0; j < 4; ++j)
          acc[ih * 4 + i2][j] = __builtin_amdgcn_mfma_f32_16x16x32_f16(
              a[i2], b[j], acc[ih * 4 + i2][j], 0, 0, 0);
      __builtin_amdgcn_s_setprio(0);
    }
  }

  // epilogue: + b_enc, non-temporal store, candidate append
  // C/D layout: col = lane&15, row = lq*4 + reg
  const int m0  = mb * 256 + wm * 128 + (lq << 2);
  const int n0g = nb * 256 + wn * 64 + l15;
#pragma unroll
  for (int j = 0; j < 4; ++j) {
    const int col = n0g + j * 16;
    const float bej = be[col];
#pragma unroll
    for (int i = 0; i < 8; ++i) {
      float* dst = &Zp[(size_t)(m0 + i * 16) * D_SAE + col];
#pragma unroll
      for (int rg = 0; rg < 4; ++rg) {
        const float o = acc[i][j][rg] + bej;
        __builtin_nontemporal_store(o, &dst[(size_t)rg * D_SAE]);
        if (o > TCAND) {
          const int row = m0 + i * 16 + rg;
          const int slot = atomicAdd(&cnt[row], 1);
          if (slot < CAP_G)
            cand[(size_t)row * CAP_G + slot] = make_uint2(__float_as_uint(o), (uint32_t)col);
        }
      }
    }
  }
}

// ---------------------------------------------------------------------------
// wave ballot-compacted LDS append
// ---------------------------------------------------------------------------
__device__ __forceinline__ void wave_append(uint32_t* dv, uint32_t* di, int* counter,
                                            bool pred, uint32_t v, uint32_t idx, int cap)
{
  const unsigned long long m = __ballot(pred ? 1 : 0);
  if (m == 0ull) return;
  const int lane = threadIdx.x & 63;
  const int leader = __ffsll(m) - 1;
  int wbase = 0;
  if (lane == leader) wbase = atomicAdd(counter, __popcll(m));
  wbase = __shfl(wbase, leader);
  if (pred) {
    const int p = wbase + (int)__popcll(m & ((1ull << lane) - 1ull));
    if (p < cap) { dv[p] = v; di[p] = idx; }
  }
}

// exact f32 partial dot over one k-octet using the split arrays
__device__ __forceinline__ float dot_oct(
    const _Float16* __restrict__ Xh, const _Float16* __restrict__ Xl,
    const _Float16* __restrict__ Wh, const _Float16* __restrict__ Wl,
    int r, int c, int go)
{
  const int kb = go >> 3, o = go & 7;
  const size_t xa = ((size_t)((r >> 7) * 12 + kb)) * 8192 +
                    (r & 127) * 64 + ((o ^ (r & 7)) << 3);
  const size_t wa = ((size_t)((c >> 7) * 12 + kb)) * 8192 +
                    (c & 127) * 64 + ((o ^ (c & 7)) << 3);
  const f16x8 xh8 = *reinterpret_cast<const f16x8*>(Xh + xa);
  const f16x8 xl8 = *reinterpret_cast<const f16x8*>(Xl + xa);
  const f16x8 wh8 = *reinterpret_cast<const f16x8*>(Wh + wa);
  const f16x8 wl8 = *reinterpret_cast<const f16x8*>(Wl + wa);
  float p = 0.0f;
#pragma unroll
  for (int e = 0; e < 8; ++e) {
    const float xf = (float)xh8[e] + (float)xl8[e] * (1.0f / 2048.0f);
    const float wf = (float)wh8[e] + (float)wl8[e] * (1.0f / 2048.0f);
    p = fmaf(xf, wf, p);
  }
  return p;
}

// ---------------------------------------------------------------------------
// select_exact: per row — approx radix top-32 (with degenerate-level skip),
// then EXACT recompute of boundary candidates (|v - v32a| <= DELTA) from the
// split arrays; final set = solid(margin > DELTA) + top-need(boundary by
// exact value, ties -> lowest index). Writes selbuf + fused decode of x_recon.
// ---------------------------------------------------------------------------
__global__ __launch_bounds__(256, 4) void select_exact(
    const float* __restrict__ Zpre, const uint2* __restrict__ cand,
    const int* __restrict__ cnt,
    const _Float16* __restrict__ Xh, const _Float16* __restrict__ Xl,
    const _Float16* __restrict__ Wh, const _Float16* __restrict__ Wl,
    const float* __restrict__ be, const float* __restrict__ Wd,
    const float* __restrict__ bd, uint2* __restrict__ selbuf,
    float* __restrict__ Xr)
{
  __shared__ uint32_t cvP[CAP_G], ciP[CAP_G];          // pristine copy
  __shared__ uint32_t cvA[CAP_G], ciA[CAP_G], cvB[CAP_G], ciB[CAP_G];
  __shared__ uint32_t hist[4][256];
  __shared__ uint32_t sel_v[KSEL], sel_i[KSEL];
  __shared__ uint32_t fsel_v[KSEL], fsel_i[KSEL];
  __shared__ uint32_t bnd_v[BCAP], bnd_i[BCAP];
  __shared__ float bex[BCAP];
  __shared__ float v32a_sh;
  __shared__ uint32_t wmin[4], wmax[4], minu_sh, maxu_sh;
  __shared__ int nc_sh, sel_sh, new_sh, bin_sh, cg_sh, nb_sh, neff_sh;

  const int row  = blockIdx.x;
  const int t    = threadIdx.x;
  const int wave = t >> 6;
  const int lane = t & 63;
  const int n_glob = cnt[row];
  int n_cur;

  if (n_glob >= KSEL && n_glob <= CAP_G) {
    // fast path: candidates pre-collected by the GEMM epilogue
    for (int j = t; j < n_glob; j += 256) {
      const uint2 p = cand[(size_t)row * CAP_G + j];
      cvP[j] = p.x; ciP[j] = p.y;
    }
    if (t == 0) neff_sh = n_glob;
    n_cur = n_glob;
    __syncthreads();
  } else {
    // rare fallback: adaptive-threshold full-row rescan of (approx) Zpre
    const float* zrow = Zpre + (size_t)row * D_SAE;
    if (t == 0) nc_sh = 0;
    __syncthreads();
    float T0 = (n_glob > CAP_G) ? 4.0f : 0.5f;
    for (int tries = 0; ; ++tries) {
      for (int j4 = t; j4 < D_SAE / 4; j4 += 256) {
        const float4 z4 = *reinterpret_cast<const float4*>(zrow + 4 * j4);
        const float zz[4] = {z4.x, z4.y, z4.z, z4.w};
#pragma unroll
        for (int c = 0; c < 4; ++c) {
          const float v = zz[c] > 0.0f ? zz[c] : 0.0f;
          wave_append(cvP, ciP, &nc_sh, v > T0, __float_as_uint(v),
                      (uint32_t)(4 * j4 + c), CAP_G);
        }
      }
      __syncthreads();
      n_cur = nc_sh;
      if ((n_cur >= KSEL && n_cur <= CAP_G) || tries >= 9) break;
      __syncthreads();
      if (t == 0) nc_sh = 0;
      T0 = (n_cur < KSEL) ? ((tries >= 6) ? 0.0f : T0 * 0.25f) : T0 * 2.0f;
      __syncthreads();
    }
    if (n_cur > CAP_G) n_cur = CAP_G;
    if (t == 0) neff_sh = n_cur;
    __syncthreads();
  }

  // ---- copy pristine -> working, and block min/max of candidate bits ----
  uint32_t lmin = 0xFFFFFFFFu, lmax = 0u;
  for (int j = t; j < n_cur; j += 256) {
    const uint32_t v = cvP[j];
    cvA[j] = v; ciA[j] = ciP[j];
    lmin = v < lmin ? v : lmin;
    lmax = v > lmax ? v : lmax;
  }
#pragma unroll
  for (int off = 32; off; off >>= 1) {
    const uint32_t omin = __shfl_xor(lmin, off), omax = __shfl_xor(lmax, off);
    lmin = omin < lmin ? omin : lmin;
    lmax = omax > lmax ? omax : lmax;
  }
  if (lane == 0) { wmin[wave] = lmin; wmax[wave] = lmax; }
  __syncthreads();
  if (t == 0) {
    uint32_t mn = 0xFFFFFFFFu, mx = 0u;
#pragma unroll
    for (int k = 0; k < 4; ++k) {
      mn = wmin[k] < mn ? wmin[k] : mn;
      mx = wmax[k] > mx ? wmax[k] : mx;
    }
    minu_sh = mn; maxu_sh = mx; sel_sh = 0;
  }
  __syncthreads();
  const uint32_t minu = minu_sh, maxu = maxu_sh;

  // ---- radix select top-32 on approx values (>= 0 => bit monotone) ----
  uint32_t* cv = cvA; uint32_t* ci = ciA;
  uint32_t* nv = cvB; uint32_t* ni = ciB;
  int need = KSEL;

  for (int L = 3; L >= 0; --L) {
    if (need <= 0 || n_cur <= 0) break;
    if (((minu ^ maxu) >> (L * 8)) == 0) continue;   // all share this byte
    hist[0][t] = 0; hist[1][t] = 0; hist[2][t] = 0; hist[3][t] = 0;
    __syncthreads();
    for (int j = t; j < n_cur; j += 256)
      atomicAdd(&hist[wave][(cv[j] >> (L * 8)) & 255u], 1u);
    __syncthreads();
    if (t == 0) {
      int cum = 0, b = 255;
      for (; b >= 0; --b) {
        const int h = (int)(hist[0][b] + hist[1][b] + hist[2][b] + hist[3][b]);
        if (cum + h >= need) break;
        cum += h;
      }
      bin_sh = b; cg_sh = cum; new_sh = 0;
    }
    __syncthreads();
    const int B = bin_sh;
    const int rounds = (n_cur + 255) / 256;
    for (int rd = 0; rd < rounds; ++rd) {
      const int j = rd * 256 + t;
      const bool valid = j < n_cur;
      const uint32_t v  = valid ? cv[j] : 0u;
      const uint32_t ix = valid ? ci[j] : 0u;
      const int by = valid ? (int)((v >> (L * 8)) & 255u) : -1;
      wave_append(sel_v, sel_i, &sel_sh, valid && by > B, v, ix, KSEL);
      wave_append(nv, ni, &new_sh, valid && by == B, v, ix, CAP_G);
    }
    __syncthreads();
    need -= cg_sh;
    n_cur = new_sh < CAP_G ? new_sh : CAP_G;
    uint32_t* tv = cv; cv = nv; nv = tv;
    uint32_t* ti = ci; ci = ni; ni = ti;
  }

  // ---- approx tie-fill (lowest indices first) + val==0 padding ----
  if (t == 0) {
    int s = sel_sh;
    const int take = (need < n_cur ? need : n_cur);
    uint32_t last = 0u; bool first = true;
    for (int r = 0; r < take; ++r) {
      uint32_t best = 0xFFFFFFFFu, bvv = 0u;
      for (int j = 0; j < n_cur; ++j) {
        const uint32_t ix = ci[j];
        if ((first || ix > last) && ix < best) { best = ix; bvv = cv[j]; }
      }
      sel_v[s] = bvv; sel_i[s] = best; ++s; last = best; first = false;
    }
    for (; s < KSEL; ++s) { sel_v[s] = 0u; sel_i[s] = 0u; }
    // v32a = min approx selected (uint min == float min for nonneg)
    uint32_t mn = 0xFFFFFFFFu;
    for (int s2 = 0; s2 < KSEL; ++s2) mn = sel_v[s2] < mn ? sel_v[s2] : mn;
    v32a_sh = __uint_as_float(mn);
    nb_sh = 0;
  }
  __syncthreads();

  const float v32a = v32a_sh;
  if (v32a > VGATE) {
    // ---- collect boundary candidates from the pristine LDS copy ----
    const int neff = neff_sh;
    for (int j0 = 0; j0 < neff; j0 += 256) {
      const int j = j0 + t;
      const bool valid = j < neff;
      const uint32_t pv = valid ? cvP[j] : 0u;
      const uint32_t pi = valid ? ciP[j] : 0u;
      const float v = __uint_as_float(pv);
      wave_append(bnd_v, bnd_i, &nb_sh, valid && fabsf(v - v32a) <= DELTA,
                  pv, pi, BCAP);
    }
    __syncthreads();
    const int nb = nb_sh < BCAP ? nb_sh : BCAP;
    // ---- exact recompute: one wave per boundary member ----
    for (int mi = wave; mi < nb; mi += 4) {
      const int col = (int)bnd_i[mi];
      float p = dot_oct(Xh, Xl, Wh, Wl, row, col, lane);
      if (lane < 32) p += dot_oct(Xh, Xl, Wh, Wl, row, col, lane + 64);
#pragma unroll
      for (int off = 32; off; off >>= 1) p += __shfl_xor(p, off);
      if (lane == 0) bex[mi] = p + be[col];
    }
    __syncthreads();
    // ---- merge: solid + top-need of boundary by (exact desc, idx asc) ----
    if (t == 0 && nb_sh > 0 && nb_sh <= BCAP) {
      const int nb2 = nb_sh;
      int ns = 0;
      const float thr = v32a + DELTA;
      for (int s = 0; s < KSEL; ++s)
        if (__uint_as_float(sel_v[s]) > thr) {
          fsel_v[ns] = sel_v[s]; fsel_i[ns] = sel_i[s]; ++ns;
        }
      const int need2 = KSEL - ns;
      unsigned long long used0 = 0ull, used1 = 0ull, used2 = 0ull;
      int filled = 0;
      for (int r2 = 0; r2 < need2; ++r2) {
        int best = -1; float bvv = -3.4e38f; uint32_t bix = 0xFFFFFFFFu;
        for (int j = 0; j < nb2; ++j) {
          const bool u = (j < 64) ? ((used0 >> j) & 1ull)
                       : (j < 128) ? ((used1 >> (j - 64)) & 1ull)
                                   : ((used2 >> (j - 128)) & 1ull);
          if (u) continue;
          const float e = bex[j];
          const uint32_t ix = bnd_i[j];
          if (e > bvv || (e == bvv && ix < bix)) { bvv = e; bix = ix; best = j; }
        }
        if (best < 0) break;
        if (best < 64) used0 |= 1ull << best;
        else if (best < 128) used1 |= 1ull << (best - 64);
        else used2 |= 1ull << (best - 128);
        const float cl = bvv > 0.0f ? bvv : 0.0f;
        fsel_v[ns + filled] = __float_as_uint(cl);
        fsel_i[ns + filled] = bix;
        ++filled;
      }
      for (int s = ns + filled; s < KSEL; ++s) { fsel_v[s] = 0u; fsel_i[s] = 0u; }
      for (int s = 0; s < KSEL; ++s) { sel_v[s] = fsel_v[s]; sel_i[s] = fsel_i[s]; }
    }
    __syncthreads();
  }

  // ---- emit selection ----
  if (t < KSEL) selbuf[row * KSEL + t] = make_uint2(sel_v[t], sel_i[t]);

  // ---- fused sparse decode: float4 loads over L3-resident Wd ----
  if (t < 192) {
    float4 a4 = *reinterpret_cast<const float4*>(&bd[4 * t]);
#pragma unroll 8
    for (int r = 0; r < KSEL; ++r) {
      const float v = __uint_as_float(sel_v[r]);
      const float4 w4 = *reinterpret_cast<const float4*>(
          &Wd[(size_t)sel_i[r] * D_MODEL + 4 * t]);
      a4.x = fmaf(v, w4.x, a4.x);
      a4.y = fmaf(v, w4.y, a4.y);
      a4.z = fmaf(v, w4.z, a4.z);
      a4.w = fmaf(v, w4.w, a4.w);
    }
    *reinterpret_cast<float4*>(&Xr[(size_t)row * D_MODEL + 4 * t]) = a4;
  }
}

// ---------------------------------------------------------------------------
// ws-too-small fallback: exact 3-pass gemm (R7-proven) + monolithic topk
// ---------------------------------------------------------------------------
__global__ __launch_bounds__(256, 3) void gemm_split3(
    const _Float16* __restrict__ Xh, const _Float16* __restrict__ Xl,
    const _Float16* __restrict__ Wh, const _Float16* __restrict__ Wl,
    const float* __restrict__ be, float* __restrict__ Zp)
{
  __shared__ char lds[32768];
  char* As = lds;
  char* Bs = lds + 16384;

  const int bid = blockIdx.x;
  const int wg  = (bid & 7) * 768 + (bid >> 3);
  const int mb  = wg & 31;
  const int nb  = wg >> 5;

  const int t = threadIdx.x, lane = t & 63, w = t >> 6;
  const int wr = w >> 1, wc = w & 1;
  const int l15 = lane & 15, lq = lane >> 4;
  const int c0 = lq ^ (lane & 7);
  const int offA0 = (wr * 64 + l15) * 128 + c0 * 16;
  const int offB0 = (wc * 64 + l15) * 128 + c0 * 16;

  f32x4 acc[4][4] = {};

  const size_t tA = (size_t)mb * 12 * 16384;
  const size_t tB = (size_t)nb * 12 * 16384;

  char* a_dst = As + (t & 192) * 16;
  char* b_dst = Bs + (t & 192) * 16;

  auto run_pass = [&](const char* Ag, const char* Bg) {
    for (int ks = 0; ks < 12; ++ks) {
      __syncthreads();
      const char* a_src = Ag + ks * 16384 + t * 16;
      const char* b_src = Bg + ks * 16384 + t * 16;
#pragma unroll
      for (int r = 0; r < 4; ++r) {
        gll16(a_dst + r * 4096, a_src + r * 4096);
        gll16(b_dst + r * 4096, b_src + r * 4096);
      }
      asm volatile("s_waitcnt vmcnt(0)" ::: "memory");
      __syncthreads();
#pragma unroll
      for (int kk = 0; kk < 2; ++kk) {
        f16x8 a[4], b[4];
#pragma unroll
        for (int i = 0; i < 4; ++i)
          a[i] = *reinterpret_cast<const f16x8*>(As + ((offA0 + i * 2048) ^ (kk * 64)));
#pragma unroll
        for (int j = 0; j < 4; ++j)
          b[j] = *reinterpret_cast<const f16x8*>(Bs + ((offB0 + j * 2048) ^ (kk * 64)));
#pragma unroll
        for (int i = 0; i < 4; ++i)
#pragma unroll
          for (int j = 0; j < 4; ++j)
            acc[i][j] = __builtin_amdgcn_mfma_f32_16x16x32_f16(a[i], b[j], acc[i][j], 0, 0, 0);
      }
    }
  };

  run_pass((const char*)Xh + tA, (const char*)Wl + tB);
  run_pass((const char*)Xl + tA, (const char*)Wh + tB);
#pragma unroll
  for (int i = 0; i < 4; ++i)
#pragma unroll
    for (int j = 0; j < 4; ++j) acc[i][j] *= (1.0f / 2048.0f);
  run_pass((const char*)Xh + tA, (const char*)Wh + tB);

  const int m0  = mb * 128 + wr * 64 + (lq << 2);
  const int n0g = nb * 128 + wc * 64 + l15;
#pragma unroll
  for (int j = 0; j < 4; ++j) {
    const int col = n0g + j * 16;
    const float bej = be[col];
#pragma unroll
    for (int i = 0; i < 4; ++i) {
      float* dst = &Zp[(size_t)(m0 + i * 16) * D_SAE + col];
#pragma unroll
      for (int rg = 0; rg < 4; ++rg)
        dst[(size_t)rg * D_SAE] = acc[i][j][rg] + bej;
    }
  }
}

#define CAP 1792
__global__ __launch_bounds__(256, 4) void topk_scatter_decode(
    const float* __restrict__ Zpre, const float* __restrict__ Wd,
    const float* __restrict__ bd, float* __restrict__ Zs, float* __restrict__ Xr)
{
  __shared__ uint32_t cvA[CAP], ciA[CAP], cvB[CAP], ciB[CAP];
  __shared__ uint32_t hist[4][256];
  __shared__ uint32_t bitmap[D_SAE / 32];
  __shared__ uint32_t sel_v[KSEL], sel_i[KSEL];
  __shared__ int nc_sh, sel_sh, new_sh, bin_sh, cg_sh;

  const int row  = blockIdx.x;
  const int t    = threadIdx.x;
  const int wave = t >> 6;
  const float* zrow = Zpre + (size_t)row * D_SAE;

  if (t == 0) nc_sh = 0;
  __syncthreads();
  float T0 = 2.0f;
  int n_cur = 0;
  for (int tries = 0; ; ++tries) {
    for (int j4 = t; j4 < D_SAE / 4; j4 += 256) {
      const float4 z4 = *reinterpret_cast<const float4*>(zrow + 4 * j4);
      const float zz[4] = {z4.x, z4.y, z4.z, z4.w};
#pragma unroll
      for (int c = 0; c < 4; ++c) {
        const float v = zz[c] > 0.0f ? zz[c] : 0.0f;
        wave_append(cvA, ciA, &nc_sh, v > T0, __float_as_uint(v),
                    (uint32_t)(4 * j4 + c), CAP);
      }
    }
    __syncthreads();
    n_cur = nc_sh;
    if ((n_cur >= KSEL && n_cur <= CAP) || tries >= 9) break;
    __syncthreads();
    if (t == 0) nc_sh = 0;
    T0 = (n_cur < KSEL) ? ((tries >= 6) ? 0.0f : T0 * 0.25f) : T0 * 2.0f;
    __syncthreads();
  }
  if (n_cur > CAP) n_cur = CAP;

  if (t == 0) sel_sh = 0;
  __syncthreads();
  uint32_t* cv = cvA; uint32_t* ci = ciA;
  uint32_t* nv = cvB; uint32_t* ni = ciB;
  int need = KSEL;

  for (int L = 3; L >= 0; --L) {
    if (need <= 0 || n_cur <= 0) break;
    hist[0][t] = 0; hist[1][t] = 0; hist[2][t] = 0; hist[3][t] = 0;
    __syncthreads();
    for (int j = t; j < n_cur; j += 256)
      atomicAdd(&hist[wave][(cv[j] >> (L * 8)) & 255u], 1u);
    __syncthreads();
    if (t == 0) {
      int cum = 0, b = 255;
      for (; b >= 0; --b) {
        const int h = (int)(hist[0][b] + hist[1][b] + hist[2][b] + hist[3][b]);
        if (cum + h >= need) break;
        cum += h;
      }
      bin_sh = b; cg_sh = cum; new_sh = 0;
    }
    __syncthreads();
    const int B = bin_sh;
    const int rounds = (n_cur + 255) / 256;
    for (int rd = 0; rd < rounds; ++rd) {
      const int j = rd * 256 + t;
      const bool valid = j < n_cur;
      const uint32_t v  = valid ? cv[j] : 0u;
      const uint32_t ix = valid ? ci[j] : 0u;
      const int by = valid ? (int)((v >> (L * 8)) & 255u) : -1;
      wave_append(sel_v, sel_i, &sel_sh, valid && by > B, v, ix, KSEL);
      wave_append(nv, ni, &new_sh, valid && by == B, v, ix, CAP);
    }
    __syncthreads();
    need -= cg_sh;
    n_cur = new_sh < CAP ? new_sh : CAP;
    uint32_t* tv = cv; cv = nv; nv = tv;
    uint32_t* ti = ci; ci = ni; ni = ti;
  }

  if (t == 0) {
    int s = sel_sh;
    const int take = (need < n_cur ? need : n_cur);
    uint32_t last = 0u; bool first = true;
    for (int r = 0; r < take; ++r) {
      uint32_t best = 0xFFFFFFFFu, bv = 0u;
      for (int j = 0; j < n_cur; ++j) {
        const uint32_t ix = ci[j];
        if ((first || ix > last) && ix < best) { best = ix; bv = cv[j]; }
      }
      sel_v[s] = bv; sel_i[s] = best; ++s; last = best; first = false;
    }
    for (; s < KSEL; ++s) { sel_v[s] = 0u; sel_i[s] = 0u; }
  }
  __syncthreads();

  bitmap[t] = 0u; bitmap[t + 256] = 0u; bitmap[t + 512] = 0u;
  __syncthreads();
  if (t < KSEL && sel_v[t] != 0u)
    atomicOr(&bitmap[sel_i[t] >> 5], 1u << (sel_i[t] & 31));
  __syncthreads();

  float* zsrow = Zs + (size_t)row * D_SAE;
  for (int j4 = t; j4 < D_SAE / 4; j4 += 256) {
    const float4 z4 = *reinterpret_cast<const float4*>(zrow + 4 * j4);
    const float zz[4] = {z4.x, z4.y, z4.z, z4.w};
    const int base = 4 * j4;
    float oo[4];
#pragma unroll
    for (int c = 0; c < 4; ++c) {
      const int idx = base + c;
      const bool sel = (bitmap[idx >> 5] >> (idx & 31)) & 1u;
      const float v = zz[c] > 0.0f ? zz[c] : 0.0f;
      oo[c] = sel ? v : 0.0f;
    }
    float4 o; o.x = oo[0]; o.y = oo[1]; o.z = oo[2]; o.w = oo[3];
    *reinterpret_cast<float4*>(zsrow + base) = o;
  }

  float a0 = bd[t], a1 = bd[t + 256], a2 = bd[t + 512];
#pragma unroll 8
  for (int r = 0; r < KSEL; ++r) {
    const float v = __uint_as_float(sel_v[r]);
    const float* wr = Wd + (size_t)sel_i[r] * D_MODEL;
    a0 = fmaf(v, wr[t], a0);
    a1 = fmaf(v, wr[t + 256], a1);
    a2 = fmaf(v, wr[t + 512], a2);
  }
  float* xrow = Xr + (size_t)row * D_MODEL;
  xrow[t] = a0; xrow[t + 256] = a1; xrow[t + 512] = a2;
}

// ---------------------------------------------------------------------------
extern "C" void kernel_launch(void* const* d_in, const int* in_sizes, int n_in,
                              void* d_out, int out_size, void* d_ws, size_t ws_size,
                              hipStream_t stream) {
  const float* X  = (const float*)d_in[0];
  const float* We = (const float*)d_in[1];
  const float* be = (const float*)d_in[2];
  const float* Wd = (const float*)d_in[3];
  const float* bd = (const float*)d_in[4];

  float* out = (float*)d_out;
  float* Xr  = out;                                   // [4096, 768]
  float* Zs  = out + (size_t)NBATCH * D_MODEL;        // [4096, 24576]
  float* Zp  = Zs + (size_t)NBATCH * D_SAE;           // [4096, 24576]

  // f16 split scratch lives in the z_sparse region (zeroed after select)
  _Float16* WhP = (_Float16*)Zs;
  _Float16* WlP = WhP + W_ELEMS;
  _Float16* XhP = WlP + W_ELEMS;
  _Float16* XlP = XhP + X_ELEMS;

  // allow 128 KB dynamic LDS for gemm8 (idempotent, capture-safe config call)
  static int lds_cfg = 0;
  if (!lds_cfg) {
    hipFuncSetAttribute((const void*)gemm8,
                        hipFuncAttributeMaxDynamicSharedMemorySize, 131072);
    lds_cfg = 1;
  }

  split_x<<<dim3(32 * 12), 256, 0, stream>>>(X, XhP, XlP);
  split_w<<<dim3(192 * 12), 256, 0, stream>>>(We, WhP, WlP);

  const size_t ws_needed = NBATCH * sizeof(int) +
                           (size_t)NBATCH * KSEL * sizeof(uint2) +
                           (size_t)NBATCH * CAP_G * sizeof(uint2);
  if (ws_size >= ws_needed) {
    int*   cnt    = (int*)d_ws;
    uint2* selbuf = (uint2*)((char*)d_ws + NBATCH * sizeof(int));
    uint2* cand   = (uint2*)((char*)d_ws + NBATCH * sizeof(int) +
                             (size_t)NBATCH * KSEL * sizeof(uint2));
    zero_cnt<<<dim3(16), 256, 0, stream>>>(cnt);
    gemm8<<<dim3(1536), 512, 131072, stream>>>(XhP, WhP, be, Zp, cand, cnt);
    select_exact<<<dim3(NBATCH), 256, 0, stream>>>(
        Zp, cand, cnt, XhP, XlP, WhP, WlP, be, Wd, bd, selbuf, Xr);
    zero_zs<<<dim3(2048), 256, 0, stream>>>(Zs);
    scatter_k<<<dim3(NBATCH * KSEL / 256), 256, 0, stream>>>(selbuf, Zs);
  } else {
    gemm_split3<<<dim3(32 * 192), 256, 0, stream>>>(XhP, XlP, WhP, WlP, be, Zp);
    topk_scatter_decode<<<dim3(NBATCH), 256, 0, stream>>>(Zp, Wd, bd, Zs, Xr);
  }
}

// Round 13
// 563.247 us; speedup vs baseline: 1.3015x; 1.3015x over previous
//
#include <hip/hip_runtime.h>
#include <cstdint>
#include <cstddef>

#define D_MODEL 768
#define D_SAE   24576
#define KSEL    32
#define NBATCH  4096

typedef _Float16 f16x8 __attribute__((ext_vector_type(8)));
typedef _Float16 f16x4 __attribute__((ext_vector_type(4)));
typedef float    f32x4 __attribute__((ext_vector_type(4)));

// f16 element counts of the split matrices (stored in the z_sparse region as scratch)
#define W_ELEMS  ((size_t)D_MODEL * D_SAE)   // 18,874,368
#define X_ELEMS  ((size_t)NBATCH * D_MODEL)  // 3,145,728

#define TCAND 2.4f      // candidate threshold (v32 per row is ~2.8-3.3)
#define CAP_G 1024      // per-row global candidate capacity
#define BCAP  160       // boundary-recompute capacity per row
#define DELTA 0.06f     // boundary half-width (~40 sigma of pairwise approx err)
#define VGATE 0.05f     // skip boundary repair when the cut is ~0 (harmless flips)
#define SORT_N 1024

// ---------------------------------------------------------------------------
// split_x: X[4096][768] f32 -> Xh,Xl' blocked f16  (xl' = (x - xh)*2^11)
// Tile = [128 m][64 k] f16 (16 KiB); element index within tile =
//   m*64 + ((k>>3) ^ (m&7))*8 + (k&7)   (XOR chunk swizzle baked in)
// ---------------------------------------------------------------------------
__global__ void split_x(const float* __restrict__ X,
                        _Float16* __restrict__ Xh, _Float16* __restrict__ Xl)
{
  const int tile = blockIdx.x;
  const int mb = tile / 12, kb = tile % 12;
  const int t = threadIdx.x;
#pragma unroll
  for (int r = 0; r < 8; ++r) {
    const int flat4 = r * 256 + t;          // 0..2047
    const int m  = flat4 >> 4;              // 0..127
    const int k4 = (flat4 & 15) << 2;       // 0,4,...,60
    const float4 v = *reinterpret_cast<const float4*>(
        &X[(size_t)(mb * 128 + m) * D_MODEL + kb * 64 + k4]);
    const float xx[4] = {v.x, v.y, v.z, v.w};
    f16x4 h, l;
#pragma unroll
    for (int c = 0; c < 4; ++c) {
      const _Float16 hh = (_Float16)xx[c];
      h[c] = hh;
      l[c] = (_Float16)((xx[c] - (float)hh) * 2048.0f);
    }
    const size_t base = ((size_t)(mb * 12 + kb)) * 8192 +
                        m * 64 + (((k4 >> 3) ^ (m & 7)) << 3) + (k4 & 7);
    *reinterpret_cast<f16x4*>(&Xh[base]) = h;
    *reinterpret_cast<f16x4*>(&Xl[base]) = l;
  }
}

// ---------------------------------------------------------------------------
// split_w: W[768][24576] f32 -> Wh,Wl' blocked-TRANSPOSED f16 tiles [n][k]
// ---------------------------------------------------------------------------
__global__ void split_w(const float* __restrict__ W,
                        _Float16* __restrict__ Wh, _Float16* __restrict__ Wl)
{
  __shared__ float Ws[64][129];
  const int tile = blockIdx.x;
  const int nb = tile / 12, kb = tile % 12;
  const int t = threadIdx.x;
#pragma unroll
  for (int r = 0; r < 8; ++r) {
    const int flat4 = r * 256 + t;
    const int k  = flat4 >> 5;              // 0..63
    const int n4 = (flat4 & 31) << 2;       // 0..124
    const float4 v = *reinterpret_cast<const float4*>(
        &W[(size_t)(kb * 64 + k) * D_SAE + nb * 128 + n4]);
    Ws[k][n4 + 0] = v.x; Ws[k][n4 + 1] = v.y; Ws[k][n4 + 2] = v.z; Ws[k][n4 + 3] = v.w;
  }
  __syncthreads();
#pragma unroll
  for (int r = 0; r < 4; ++r) {
    const int u = r * 256 + t;              // 0..1023
    const int n = u >> 3;                   // 0..127
    const int c = u & 7;                    // k-octet
    f16x8 h, l;
#pragma unroll
    for (int i = 0; i < 8; ++i) {
      const float w = Ws[c * 8 + i][n];
      const _Float16 hh = (_Float16)w;
      h[i] = hh;
      l[i] = (_Float16)((w - (float)hh) * 2048.0f);
    }
    const size_t base = ((size_t)(nb * 12 + kb)) * 8192 + n * 64 + ((c ^ (n & 7)) << 3);
    *reinterpret_cast<f16x8*>(&Wh[base]) = h;
    *reinterpret_cast<f16x8*>(&Wl[base]) = l;
  }
}

// ---------------------------------------------------------------------------
__global__ void zero_cnt(int* cnt) { cnt[blockIdx.x * 256 + threadIdx.x] = 0; }

// zero_scatter: per row, stream zeros (non-temporal) then scatter the 32
// selected values (zero_zs + scatter_k merged; barrier orders the writes)
__global__ __launch_bounds__(256) void zero_scatter(const uint2* __restrict__ selbuf,
                                                    float* __restrict__ Zs)
{
  const int row = blockIdx.x, t = threadIdx.x;
  float* zsrow = Zs + (size_t)row * D_SAE;
  const f32x4 z = {0.0f, 0.0f, 0.0f, 0.0f};
  f32x4* p4 = reinterpret_cast<f32x4*>(zsrow);
#pragma unroll
  for (int r = 0; r < 24; ++r)
    __builtin_nontemporal_store(z, p4 + r * 256 + t);
  __syncthreads();
  if (t < KSEL) {
    const uint2 p = selbuf[row * KSEL + t];
    if (p.x) zsrow[p.y] = __uint_as_float(p.x);
  }
}

// ---------------------------------------------------------------------------
__device__ __forceinline__ void gll16(void* lds, const void* g) {
  __builtin_amdgcn_global_load_lds(
      (const __attribute__((address_space(1))) unsigned int*)g,
      (__attribute__((address_space(3))) unsigned int*)lds, 16, 0, 0);
}

// ---------------------------------------------------------------------------
// gemm_f16: ONE-pass approx GEMM  Zp = Xh@Wh + be  (R7/R11-proven structure:
// 128x128 tile, BK=64, 32 KB LDS, drain loop, 3+ blocks/CU).
// Epilogue: non-temporal Zp store + candidate append (> TCAND).
// ---------------------------------------------------------------------------
__global__ __launch_bounds__(256, 3) void gemm_f16(
    const _Float16* __restrict__ Xh, const _Float16* __restrict__ Wh,
    const float* __restrict__ be, float* __restrict__ Zp,
    uint2* __restrict__ cand, int* __restrict__ cnt)
{
  __shared__ char lds[32768];
  char* As = lds;
  char* Bs = lds + 16384;

  const int bid = blockIdx.x;
  const int wg  = (bid & 7) * 768 + (bid >> 3);   // XCD-contiguous chunks
  const int mb  = wg & 31;
  const int nb  = wg >> 5;

  const int t = threadIdx.x, lane = t & 63, w = t >> 6;
  const int wr = w >> 1, wc = w & 1;
  const int l15 = lane & 15, lq = lane >> 4;
  const int c0 = lq ^ (lane & 7);
  const int offA0 = (wr * 64 + l15) * 128 + c0 * 16;
  const int offB0 = (wc * 64 + l15) * 128 + c0 * 16;

  f32x4 acc[4][4] = {};

  const char* Ag = (const char*)Xh + (size_t)mb * 12 * 16384;
  const char* Bg = (const char*)Wh + (size_t)nb * 12 * 16384;

  char* a_dst = As + (t & 192) * 16;
  char* b_dst = Bs + (t & 192) * 16;

  for (int ks = 0; ks < 12; ++ks) {
    __syncthreads();
    const char* a_src = Ag + ks * 16384 + t * 16;
    const char* b_src = Bg + ks * 16384 + t * 16;
#pragma unroll
    for (int r = 0; r < 4; ++r) {
      gll16(a_dst + r * 4096, a_src + r * 4096);
      gll16(b_dst + r * 4096, b_src + r * 4096);
    }
    asm volatile("s_waitcnt vmcnt(0)" ::: "memory");
    __syncthreads();
#pragma unroll
    for (int kk = 0; kk < 2; ++kk) {
      f16x8 a[4], b[4];
#pragma unroll
      for (int i = 0; i < 4; ++i)
        a[i] = *reinterpret_cast<const f16x8*>(As + ((offA0 + i * 2048) ^ (kk * 64)));
#pragma unroll
      for (int j = 0; j < 4; ++j)
        b[j] = *reinterpret_cast<const f16x8*>(Bs + ((offB0 + j * 2048) ^ (kk * 64)));
#pragma unroll
      for (int i = 0; i < 4; ++i)
#pragma unroll
        for (int j = 0; j < 4; ++j)
          acc[i][j] = __builtin_amdgcn_mfma_f32_16x16x32_f16(a[i], b[j], acc[i][j], 0, 0, 0);
    }
  }

  // epilogue: + b_enc, non-temporal store, candidate append
  // C/D layout: col = lane&15, row = lq*4 + reg
  const int m0  = mb * 128 + wr * 64 + (lq << 2);
  const int n0g = nb * 128 + wc * 64 + l15;
#pragma unroll
  for (int j = 0; j < 4; ++j) {
    const int col = n0g + j * 16;
    const float bej = be[col];
#pragma unroll
    for (int i = 0; i < 4; ++i) {
      float* dst = &Zp[(size_t)(m0 + i * 16) * D_SAE + col];
#pragma unroll
      for (int rg = 0; rg < 4; ++rg) {
        const float o = acc[i][j][rg] + bej;
        __builtin_nontemporal_store(o, &dst[(size_t)rg * D_SAE]);
        if (o > TCAND) {
          const int row = m0 + i * 16 + rg;
          const int slot = atomicAdd(&cnt[row], 1);
          if (slot < CAP_G)
            cand[(size_t)row * CAP_G + slot] = make_uint2(__float_as_uint(o), (uint32_t)col);
        }
      }
    }
  }
}

// ---------------------------------------------------------------------------
// wave ballot-compacted appends
// ---------------------------------------------------------------------------
__device__ __forceinline__ void wave_append(uint32_t* dv, uint32_t* di, int* counter,
                                            bool pred, uint32_t v, uint32_t idx, int cap)
{
  const unsigned long long m = __ballot(pred ? 1 : 0);
  if (m == 0ull) return;
  const int lane = threadIdx.x & 63;
  const int leader = __ffsll(m) - 1;
  int wbase = 0;
  if (lane == leader) wbase = atomicAdd(counter, __popcll(m));
  wbase = __shfl(wbase, leader);
  if (pred) {
    const int p = wbase + (int)__popcll(m & ((1ull << lane) - 1ull));
    if (p < cap) { dv[p] = v; di[p] = idx; }
  }
}

__device__ __forceinline__ void wave_append64(unsigned long long* dv, int* counter,
                                              bool pred, unsigned long long key, int cap)
{
  const unsigned long long m = __ballot(pred ? 1 : 0);
  if (m == 0ull) return;
  const int lane = threadIdx.x & 63;
  const int leader = __ffsll(m) - 1;
  int wbase = 0;
  if (lane == leader) wbase = atomicAdd(counter, __popcll(m));
  wbase = __shfl(wbase, leader);
  if (pred) {
    const int p = wbase + (int)__popcll(m & ((1ull << lane) - 1ull));
    if (p < cap) dv[p] = key;
  }
}

// exact f32 partial dot over one k-octet using the split arrays
__device__ __forceinline__ float dot_oct(
    const _Float16* __restrict__ Xh, const _Float16* __restrict__ Xl,
    const _Float16* __restrict__ Wh, const _Float16* __restrict__ Wl,
    int r, int c, int go)
{
  const int kb = go >> 3, o = go & 7;
  const size_t xa = ((size_t)((r >> 7) * 12 + kb)) * 8192 +
                    (r & 127) * 64 + ((o ^ (r & 7)) << 3);
  const size_t wa = ((size_t)((c >> 7) * 12 + kb)) * 8192 +
                    (c & 127) * 64 + ((o ^ (c & 7)) << 3);
  const f16x8 xh8 = *reinterpret_cast<const f16x8*>(Xh + xa);
  const f16x8 xl8 = *reinterpret_cast<const f16x8*>(Xl + xa);
  const f16x8 wh8 = *reinterpret_cast<const f16x8*>(Wh + wa);
  const f16x8 wl8 = *reinterpret_cast<const f16x8*>(Wl + wa);
  float p = 0.0f;
#pragma unroll
  for (int e = 0; e < 8; ++e) {
    const float xf = (float)xh8[e] + (float)xl8[e] * (1.0f / 2048.0f);
    const float wf = (float)wh8[e] + (float)wl8[e] * (1.0f / 2048.0f);
    p = fmaf(xf, wf, p);
  }
  return p;
}

// ---------------------------------------------------------------------------
// select_exact: per row — pack candidates as key=(~vbits<<32)|idx, bitonic
// sort ascending (== value desc, idx asc: exact jax top_k tie semantics),
// exact-recompute the boundary band [lo,hi) in-place, re-sort, take first 32.
// NO serial t==0 loops. Writes selbuf + fused decode of x_recon.
// ---------------------------------------------------------------------------
__global__ __launch_bounds__(256, 4) void select_exact(
    const float* __restrict__ Zpre, const uint2* __restrict__ cand,
    const int* __restrict__ cnt,
    const _Float16* __restrict__ Xh, const _Float16* __restrict__ Xl,
    const _Float16* __restrict__ Wh, const _Float16* __restrict__ Wl,
    const float* __restrict__ be, const float* __restrict__ Wd,
    const float* __restrict__ bd, uint2* __restrict__ selbuf,
    float* __restrict__ Xr)
{
  __shared__ unsigned long long kv[SORT_N];
  __shared__ int nc_sh, lo_sh, hi_sh;

  const int row  = blockIdx.x;
  const int t    = threadIdx.x;
  const int wave = t >> 6;
  const int lane = t & 63;
  const int n_glob = cnt[row];
  int n;

  const unsigned long long PAD = 0xFFFFFFFF00000000ull;   // v=0, idx=0

  if (n_glob >= KSEL && n_glob <= CAP_G) {
    // fast path: candidates pre-collected by the GEMM epilogue
    n = n_glob;
    for (int j = t; j < SORT_N; j += 256) {
      unsigned long long key = PAD;
      if (j < n) {
        const uint2 p = cand[(size_t)row * CAP_G + j];
        key = ((unsigned long long)(~p.x) << 32) | p.y;
      }
      kv[j] = key;
    }
    __syncthreads();
  } else {
    // rare fallback: adaptive-threshold full-row rescan of (approx) Zpre
    const float* zrow = Zpre + (size_t)row * D_SAE;
    float T0 = (n_glob > CAP_G) ? 4.0f : 0.5f;
    for (int tries = 0; ; ++tries) {
      for (int j = t; j < SORT_N; j += 256) kv[j] = PAD;
      if (t == 0) nc_sh = 0;
      __syncthreads();
      for (int j4 = t; j4 < D_SAE / 4; j4 += 256) {
        const float4 z4 = *reinterpret_cast<const float4*>(zrow + 4 * j4);
        const float zz[4] = {z4.x, z4.y, z4.z, z4.w};
#pragma unroll
        for (int c = 0; c < 4; ++c) {
          const float v = zz[c] > 0.0f ? zz[c] : 0.0f;
          const unsigned long long key =
              ((unsigned long long)(~__float_as_uint(v)) << 32) | (uint32_t)(4 * j4 + c);
          wave_append64(kv, &nc_sh, v > T0, key, SORT_N);
        }
      }
      __syncthreads();
      n = nc_sh > SORT_N ? SORT_N : nc_sh;
      if ((nc_sh >= KSEL && nc_sh <= SORT_N) || tries >= 9) break;
      T0 = (nc_sh < KSEL) ? ((tries >= 6) ? 0.0f : T0 * 0.25f) : T0 * 2.0f;
      __syncthreads();
    }
    // dropped (>cap) entries leave holes? no: appends are contiguous [0,nc_sh)
    __syncthreads();
  }

  const int NS = (n <= 512) ? 512 : SORT_N;   // sort width (uniform per block)

  // ---- bitonic sort ascending over kv[0..NS) ----
  auto bitonic = [&]() {
    for (int k = 2; k <= NS; k <<= 1)
      for (int j2 = k >> 1; j2 > 0; j2 >>= 1) {
        __syncthreads();
        for (int i = t; i < NS; i += 256) {
          const int ixj = i ^ j2;
          if (ixj > i) {
            const unsigned long long a = kv[i], b = kv[ixj];
            const bool up = (i & k) == 0;
            if ((a > b) == up) { kv[i] = b; kv[ixj] = a; }
          }
        }
      }
    __syncthreads();
  };

  bitonic();

  const float v32a = __uint_as_float(~(uint32_t)(kv[KSEL - 1] >> 32));

  if (v32a > VGATE) {
    // ---- find band [lo,hi): lo = #(v > v32a+DELTA), hi = #(v >= v32a-DELTA)
    if (t == 0) { lo_sh = 0; hi_sh = 0; }
    __syncthreads();
    int chi = 0, clo = 0;
    for (int j = t; j < n; j += 256) {
      const float v = __uint_as_float(~(uint32_t)(kv[j] >> 32));
      chi += (v > v32a + DELTA) ? 1 : 0;
      clo += (v >= v32a - DELTA) ? 1 : 0;
    }
#pragma unroll
    for (int off = 32; off; off >>= 1) {
      chi += __shfl_xor(chi, off);
      clo += __shfl_xor(clo, off);
    }
    if (lane == 0) { atomicAdd(&lo_sh, chi); atomicAdd(&hi_sh, clo); }
    __syncthreads();
    const int lo = lo_sh;
    int hi = hi_sh;
    if (hi > lo + BCAP) hi = lo + BCAP;

    // ---- exact recompute of band members (one wave per member), in place ----
    for (int mi = lo + wave; mi < hi; mi += 4) {
      const int col = (int)(uint32_t)kv[mi];
      float p = dot_oct(Xh, Xl, Wh, Wl, row, col, lane);
      if (lane < 32) p += dot_oct(Xh, Xl, Wh, Wl, row, col, lane + 64);
#pragma unroll
      for (int off = 32; off; off >>= 1) p += __shfl_xor(p, off);
      if (lane == 0) {
        float e = p + be[col];
        e = e > 0.0f ? e : 0.0f;
        kv[mi] = ((unsigned long long)(~__float_as_uint(e)) << 32) | (uint32_t)col;
      }
    }
    __syncthreads();
    bitonic();                          // re-sort with exact band values
  }

  // ---- emit selection (first 32 of sorted order) ----
  if (t < KSEL) {
    const unsigned long long key = kv[t];
    selbuf[row * KSEL + t] = make_uint2(~(uint32_t)(key >> 32), (uint32_t)key);
  }

  // ---- fused sparse decode: float4 loads over L3-resident Wd ----
  if (t < 192) {
    float4 a4 = *reinterpret_cast<const float4*>(&bd[4 * t]);
#pragma unroll 8
    for (int r = 0; r < KSEL; ++r) {
      const unsigned long long key = kv[r];
      const float v = __uint_as_float(~(uint32_t)(key >> 32));
      const float4 w4 = *reinterpret_cast<const float4*>(
          &Wd[(size_t)(uint32_t)key * D_MODEL + 4 * t]);
      a4.x = fmaf(v, w4.x, a4.x);
      a4.y = fmaf(v, w4.y, a4.y);
      a4.z = fmaf(v, w4.z, a4.z);
      a4.w = fmaf(v, w4.w, a4.w);
    }
    *reinterpret_cast<float4*>(&Xr[(size_t)row * D_MODEL + 4 * t]) = a4;
  }
}

// ---------------------------------------------------------------------------
// ws-too-small fallback: exact 3-pass gemm (R7-proven) + monolithic topk
// ---------------------------------------------------------------------------
__global__ __launch_bounds__(256, 3) void gemm_split3(
    const _Float16* __restrict__ Xh, const _Float16* __restrict__ Xl,
    const _Float16* __restrict__ Wh, const _Float16* __restrict__ Wl,
    const float* __restrict__ be, float* __restrict__ Zp)
{
  __shared__ char lds[32768];
  char* As = lds;
  char* Bs = lds + 16384;

  const int bid = blockIdx.x;
  const int wg  = (bid & 7) * 768 + (bid >> 3);
  const int mb  = wg & 31;
  const int nb  = wg >> 5;

  const int t = threadIdx.x, lane = t & 63, w = t >> 6;
  const int wr = w >> 1, wc = w & 1;
  const int l15 = lane & 15, lq = lane >> 4;
  const int c0 = lq ^ (lane & 7);
  const int offA0 = (wr * 64 + l15) * 128 + c0 * 16;
  const int offB0 = (wc * 64 + l15) * 128 + c0 * 16;

  f32x4 acc[4][4] = {};

  const size_t tA = (size_t)mb * 12 * 16384;
  const size_t tB = (size_t)nb * 12 * 16384;

  char* a_dst = As + (t & 192) * 16;
  char* b_dst = Bs + (t & 192) * 16;

  auto run_pass = [&](const char* Ag, const char* Bg) {
    for (int ks = 0; ks < 12; ++ks) {
      __syncthreads();
      const char* a_src = Ag + ks * 16384 + t * 16;
      const char* b_src = Bg + ks * 16384 + t * 16;
#pragma unroll
      for (int r = 0; r < 4; ++r) {
        gll16(a_dst + r * 4096, a_src + r * 4096);
        gll16(b_dst + r * 4096, b_src + r * 4096);
      }
      asm volatile("s_waitcnt vmcnt(0)" ::: "memory");
      __syncthreads();
#pragma unroll
      for (int kk = 0; kk < 2; ++kk) {
        f16x8 a[4], b[4];
#pragma unroll
        for (int i = 0; i < 4; ++i)
          a[i] = *reinterpret_cast<const f16x8*>(As + ((offA0 + i * 2048) ^ (kk * 64)));
#pragma unroll
        for (int j = 0; j < 4; ++j)
          b[j] = *reinterpret_cast<const f16x8*>(Bs + ((offB0 + j * 2048) ^ (kk * 64)));
#pragma unroll
        for (int i = 0; i < 4; ++i)
#pragma unroll
          for (int j = 0; j < 4; ++j)
            acc[i][j] = __builtin_amdgcn_mfma_f32_16x16x32_f16(a[i], b[j], acc[i][j], 0, 0, 0);
      }
    }
  };

  run_pass((const char*)Xh + tA, (const char*)Wl + tB);
  run_pass((const char*)Xl + tA, (const char*)Wh + tB);
#pragma unroll
  for (int i = 0; i < 4; ++i)
#pragma unroll
    for (int j = 0; j < 4; ++j) acc[i][j] *= (1.0f / 2048.0f);
  run_pass((const char*)Xh + tA, (const char*)Wh + tB);

  const int m0  = mb * 128 + wr * 64 + (lq << 2);
  const int n0g = nb * 128 + wc * 64 + l15;
#pragma unroll
  for (int j = 0; j < 4; ++j) {
    const int col = n0g + j * 16;
    const float bej = be[col];
#pragma unroll
    for (int i = 0; i < 4; ++i) {
      float* dst = &Zp[(size_t)(m0 + i * 16) * D_SAE + col];
#pragma unroll
      for (int rg = 0; rg < 4; ++rg)
        dst[(size_t)rg * D_SAE] = acc[i][j][rg] + bej;
    }
  }
}

#define CAP 1792
__global__ __launch_bounds__(256, 4) void topk_scatter_decode(
    const float* __restrict__ Zpre, const float* __restrict__ Wd,
    const float* __restrict__ bd, float* __restrict__ Zs, float* __restrict__ Xr)
{
  __shared__ uint32_t cvA[CAP], ciA[CAP], cvB[CAP], ciB[CAP];
  __shared__ uint32_t hist[4][256];
  __shared__ uint32_t bitmap[D_SAE / 32];
  __shared__ uint32_t sel_v[KSEL], sel_i[KSEL];
  __shared__ int nc_sh, sel_sh, new_sh, bin_sh, cg_sh;

  const int row  = blockIdx.x;
  const int t    = threadIdx.x;
  const int wave = t >> 6;
  const float* zrow = Zpre + (size_t)row * D_SAE;

  if (t == 0) nc_sh = 0;
  __syncthreads();
  float T0 = 2.0f;
  int n_cur = 0;
  for (int tries = 0; ; ++tries) {
    for (int j4 = t; j4 < D_SAE / 4; j4 += 256) {
      const float4 z4 = *reinterpret_cast<const float4*>(zrow + 4 * j4);
      const float zz[4] = {z4.x, z4.y, z4.z, z4.w};
#pragma unroll
      for (int c = 0; c < 4; ++c) {
        const float v = zz[c] > 0.0f ? zz[c] : 0.0f;
        wave_append(cvA, ciA, &nc_sh, v > T0, __float_as_uint(v),
                    (uint32_t)(4 * j4 + c), CAP);
      }
    }
    __syncthreads();
    n_cur = nc_sh;
    if ((n_cur >= KSEL && n_cur <= CAP) || tries >= 9) break;
    __syncthreads();
    if (t == 0) nc_sh = 0;
    T0 = (n_cur < KSEL) ? ((tries >= 6) ? 0.0f : T0 * 0.25f) : T0 * 2.0f;
    __syncthreads();
  }
  if (n_cur > CAP) n_cur = CAP;

  if (t == 0) sel_sh = 0;
  __syncthreads();
  uint32_t* cv = cvA; uint32_t* ci = ciA;
  uint32_t* nv = cvB; uint32_t* ni = ciB;
  int need = KSEL;

  for (int L = 3; L >= 0; --L) {
    if (need <= 0 || n_cur <= 0) break;
    hist[0][t] = 0; hist[1][t] = 0; hist[2][t] = 0; hist[3][t] = 0;
    __syncthreads();
    for (int j = t; j < n_cur; j += 256)
      atomicAdd(&hist[wave][(cv[j] >> (L * 8)) & 255u], 1u);
    __syncthreads();
    if (t == 0) {
      int cum = 0, b = 255;
      for (; b >= 0; --b) {
        const int h = (int)(hist[0][b] + hist[1][b] + hist[2][b] + hist[3][b]);
        if (cum + h >= need) break;
        cum += h;
      }
      bin_sh = b; cg_sh = cum; new_sh = 0;
    }
    __syncthreads();
    const int B = bin_sh;
    const int rounds = (n_cur + 255) / 256;
    for (int rd = 0; rd < rounds; ++rd) {
      const int j = rd * 256 + t;
      const bool valid = j < n_cur;
      const uint32_t v  = valid ? cv[j] : 0u;
      const uint32_t ix = valid ? ci[j] : 0u;
      const int by = valid ? (int)((v >> (L * 8)) & 255u) : -1;
      wave_append(sel_v, sel_i, &sel_sh, valid && by > B, v, ix, KSEL);
      wave_append(nv, ni, &new_sh, valid && by == B, v, ix, CAP);
    }
    __syncthreads();
    need -= cg_sh;
    n_cur = new_sh < CAP ? new_sh : CAP;
    uint32_t* tv = cv; cv = nv; nv = tv;
    uint32_t* ti = ci; ci = ni; ni = ti;
  }

  if (t == 0) {
    int s = sel_sh;
    const int take = (need < n_cur ? need : n_cur);
    uint32_t last = 0u; bool first = true;
    for (int r = 0; r < take; ++r) {
      uint32_t best = 0xFFFFFFFFu, bv = 0u;
      for (int j = 0; j < n_cur; ++j) {
        const uint32_t ix = ci[j];
        if ((first || ix > last) && ix < best) { best = ix; bv = cv[j]; }
      }
      sel_v[s] = bv; sel_i[s] = best; ++s; last = best; first = false;
    }
    for (; s < KSEL; ++s) { sel_v[s] = 0u; sel_i[s] = 0u; }
  }
  __syncthreads();

  bitmap[t] = 0u; bitmap[t + 256] = 0u; bitmap[t + 512] = 0u;
  __syncthreads();
  if (t < KSEL && sel_v[t] != 0u)
    atomicOr(&bitmap[sel_i[t] >> 5], 1u << (sel_i[t] & 31));
  __syncthreads();

  float* zsrow = Zs + (size_t)row * D_SAE;
  for (int j4 = t; j4 < D_SAE / 4; j4 += 256) {
    const float4 z4 = *reinterpret_cast<const float4*>(zrow + 4 * j4);
    const float zz[4] = {z4.x, z4.y, z4.z, z4.w};
    const int base = 4 * j4;
    float oo[4];
#pragma unroll
    for (int c = 0; c < 4; ++c) {
      const int idx = base + c;
      const bool sel = (bitmap[idx >> 5] >> (idx & 31)) & 1u;
      const float v = zz[c] > 0.0f ? zz[c] : 0.0f;
      oo[c] = sel ? v : 0.0f;
    }
    float4 o; o.x = oo[0]; o.y = oo[1]; o.z = oo[2]; o.w = oo[3];
    *reinterpret_cast<float4*>(zsrow + base) = o;
  }

  float a0 = bd[t], a1 = bd[t + 256], a2 = bd[t + 512];
#pragma unroll 8
  for (int r = 0; r < KSEL; ++r) {
    const float v = __uint_as_float(sel_v[r]);
    const float* wr = Wd + (size_t)sel_i[r] * D_MODEL;
    a0 = fmaf(v, wr[t], a0);
    a1 = fmaf(v, wr[t + 256], a1);
    a2 = fmaf(v, wr[t + 512], a2);
  }
  float* xrow = Xr + (size_t)row * D_MODEL;
  xrow[t] = a0; xrow[t + 256] = a1; xrow[t + 512] = a2;
}

// ---------------------------------------------------------------------------
extern "C" void kernel_launch(void* const* d_in, const int* in_sizes, int n_in,
                              void* d_out, int out_size, void* d_ws, size_t ws_size,
                              hipStream_t stream) {
  const float* X  = (const float*)d_in[0];
  const float* We = (const float*)d_in[1];
  const float* be = (const float*)d_in[2];
  const float* Wd = (const float*)d_in[3];
  const float* bd = (const float*)d_in[4];

  float* out = (float*)d_out;
  float* Xr  = out;                                   // [4096, 768]
  float* Zs  = out + (size_t)NBATCH * D_MODEL;        // [4096, 24576]
  float* Zp  = Zs + (size_t)NBATCH * D_SAE;           // [4096, 24576]

  // f16 split scratch lives in the z_sparse region (zeroed after select)
  _Float16* WhP = (_Float16*)Zs;
  _Float16* WlP = WhP + W_ELEMS;
  _Float16* XhP = WlP + W_ELEMS;
  _Float16* XlP = XhP + X_ELEMS;

  split_x<<<dim3(32 * 12), 256, 0, stream>>>(X, XhP, XlP);
  split_w<<<dim3(192 * 12), 256, 0, stream>>>(We, WhP, WlP);

  const size_t ws_needed = NBATCH * sizeof(int) +
                           (size_t)NBATCH * KSEL * sizeof(uint2) +
                           (size_t)NBATCH * CAP_G * sizeof(uint2);
  if (ws_size >= ws_needed) {
    int*   cnt    = (int*)d_ws;
    uint2* selbuf = (uint2*)((char*)d_ws + NBATCH * sizeof(int));
    uint2* cand   = (uint2*)((char*)d_ws + NBATCH * sizeof(int) +
                             (size_t)NBATCH * KSEL * sizeof(uint2));
    zero_cnt<<<dim3(16), 256, 0, stream>>>(cnt);
    gemm_f16<<<dim3(32 * 192), 256, 0, stream>>>(XhP, WhP, be, Zp, cand, cnt);
    select_exact<<<dim3(NBATCH), 256, 0, stream>>>(
        Zp, cand, cnt, XhP, XlP, WhP, WlP, be, Wd, bd, selbuf, Xr);
    zero_scatter<<<dim3(NBATCH), 256, 0, stream>>>(selbuf, Zs);
  } else {
    gemm_split3<<<dim3(32 * 192), 256, 0, stream>>>(XhP, XlP, WhP, WlP, be, Zp);
    topk_scatter_decode<<<dim3(NBATCH), 256, 0, stream>>>(Zp, Wd, bd, Zs, Xr);
  }
}

// Round 14
// 460.906 us; speedup vs baseline: 1.5905x; 1.2220x over previous
//
#include <hip/hip_runtime.h>
#include <cstdint>
#include <cstddef>

#define D_MODEL 768
#define D_SAE   24576
#define KSEL    32
#define NBATCH  4096

typedef _Float16 f16x8 __attribute__((ext_vector_type(8)));
typedef _Float16 f16x4 __attribute__((ext_vector_type(4)));
typedef float    f32x4 __attribute__((ext_vector_type(4)));

// f16 element counts of the split matrices (stored in the z_sparse region as scratch)
#define W_ELEMS  ((size_t)D_MODEL * D_SAE)   // 18,874,368
#define X_ELEMS  ((size_t)NBATCH * D_MODEL)  // 3,145,728
// scratch = 88,080,384 B = exactly 896 Zs rows; rows >= 1024 are scratch-free
#define ZROW_SPLIT 1024

#define TCAND 2.4f      // candidate threshold (v32 per row is ~2.8-3.3)
#define CAP_G 1024      // per-row global candidate capacity
#define BCAP  160       // boundary-recompute capacity per row
#define DELTA 0.06f     // boundary half-width (~40 sigma of pairwise approx err)
#define VGATE 0.05f     // skip boundary repair when the cut is ~0 (harmless flips)
#define SORT_N 1024

// ---------------------------------------------------------------------------
// split_x: X[4096][768] f32 -> Xh,Xl' blocked f16  (xl' = (x - xh)*2^11)
// ---------------------------------------------------------------------------
__global__ void split_x(const float* __restrict__ X,
                        _Float16* __restrict__ Xh, _Float16* __restrict__ Xl)
{
  const int tile = blockIdx.x;
  const int mb = tile / 12, kb = tile % 12;
  const int t = threadIdx.x;
#pragma unroll
  for (int r = 0; r < 8; ++r) {
    const int flat4 = r * 256 + t;          // 0..2047
    const int m  = flat4 >> 4;              // 0..127
    const int k4 = (flat4 & 15) << 2;       // 0,4,...,60
    const float4 v = *reinterpret_cast<const float4*>(
        &X[(size_t)(mb * 128 + m) * D_MODEL + kb * 64 + k4]);
    const float xx[4] = {v.x, v.y, v.z, v.w};
    f16x4 h, l;
#pragma unroll
    for (int c = 0; c < 4; ++c) {
      const _Float16 hh = (_Float16)xx[c];
      h[c] = hh;
      l[c] = (_Float16)((xx[c] - (float)hh) * 2048.0f);
    }
    const size_t base = ((size_t)(mb * 12 + kb)) * 8192 +
                        m * 64 + (((k4 >> 3) ^ (m & 7)) << 3) + (k4 & 7);
    *reinterpret_cast<f16x4*>(&Xh[base]) = h;
    *reinterpret_cast<f16x4*>(&Xl[base]) = l;
  }
}

// ---------------------------------------------------------------------------
// split_w: W[768][24576] f32 -> Wh,Wl' blocked-TRANSPOSED f16 tiles [n][k]
// ---------------------------------------------------------------------------
__global__ void split_w(const float* __restrict__ W,
                        _Float16* __restrict__ Wh, _Float16* __restrict__ Wl)
{
  __shared__ float Ws[64][129];
  const int tile = blockIdx.x;
  const int nb = tile / 12, kb = tile % 12;
  const int t = threadIdx.x;
#pragma unroll
  for (int r = 0; r < 8; ++r) {
    const int flat4 = r * 256 + t;
    const int k  = flat4 >> 5;              // 0..63
    const int n4 = (flat4 & 31) << 2;       // 0..124
    const float4 v = *reinterpret_cast<const float4*>(
        &W[(size_t)(kb * 64 + k) * D_SAE + nb * 128 + n4]);
    Ws[k][n4 + 0] = v.x; Ws[k][n4 + 1] = v.y; Ws[k][n4 + 2] = v.z; Ws[k][n4 + 3] = v.w;
  }
  __syncthreads();
#pragma unroll
  for (int r = 0; r < 4; ++r) {
    const int u = r * 256 + t;              // 0..1023
    const int n = u >> 3;                   // 0..127
    const int c = u & 7;                    // k-octet
    f16x8 h, l;
#pragma unroll
    for (int i = 0; i < 8; ++i) {
      const float w = Ws[c * 8 + i][n];
      const _Float16 hh = (_Float16)w;
      h[i] = hh;
      l[i] = (_Float16)((w - (float)hh) * 2048.0f);
    }
    const size_t base = ((size_t)(nb * 12 + kb)) * 8192 + n * 64 + ((c ^ (n & 7)) << 3);
    *reinterpret_cast<f16x8*>(&Wh[base]) = h;
    *reinterpret_cast<f16x8*>(&Wl[base]) = l;
  }
}

// ---------------------------------------------------------------------------
__global__ void zero_cnt(int* cnt) { cnt[blockIdx.x * 256 + threadIdx.x] = 0; }

// zero_scatter: rows < ZROW_SPLIT only (scratch region; runs after select)
__global__ __launch_bounds__(256) void zero_scatter(const uint2* __restrict__ selbuf,
                                                    float* __restrict__ Zs)
{
  const int row = blockIdx.x, t = threadIdx.x;
  float* zsrow = Zs + (size_t)row * D_SAE;
  const f32x4 z = {0.0f, 0.0f, 0.0f, 0.0f};
  f32x4* p4 = reinterpret_cast<f32x4*>(zsrow);
#pragma unroll
  for (int r = 0; r < 24; ++r)
    __builtin_nontemporal_store(z, p4 + r * 256 + t);
  __syncthreads();
  if (t < KSEL) {
    const uint2 p = selbuf[row * KSEL + t];
    if (p.x) zsrow[p.y] = __uint_as_float(p.x);
  }
}

// ---------------------------------------------------------------------------
__device__ __forceinline__ void gll16(void* lds, const void* g) {
  __builtin_amdgcn_global_load_lds(
      (const __attribute__((address_space(1))) unsigned int*)g,
      (__attribute__((address_space(3))) unsigned int*)lds, 16, 0, 0);
}

// ---------------------------------------------------------------------------
// gemm_f16: ONE-pass approx GEMM  Zp = Xh@Wh + be  (R7/R11-proven structure:
// 128x128 tile, BK=64, 32 KB LDS, drain loop, 3+ blocks/CU).
// Epilogue: non-temporal Zp store + candidate append (> TCAND).
// ---------------------------------------------------------------------------
__global__ __launch_bounds__(256, 3) void gemm_f16(
    const _Float16* __restrict__ Xh, const _Float16* __restrict__ Wh,
    const float* __restrict__ be, float* __restrict__ Zp,
    uint2* __restrict__ cand, int* __restrict__ cnt)
{
  __shared__ char lds[32768];
  char* As = lds;
  char* Bs = lds + 16384;

  const int bid = blockIdx.x;
  const int wg  = (bid & 7) * 768 + (bid >> 3);   // XCD-contiguous chunks
  const int mb  = wg & 31;
  const int nb  = wg >> 5;

  const int t = threadIdx.x, lane = t & 63, w = t >> 6;
  const int wr = w >> 1, wc = w & 1;
  const int l15 = lane & 15, lq = lane >> 4;
  const int c0 = lq ^ (lane & 7);
  const int offA0 = (wr * 64 + l15) * 128 + c0 * 16;
  const int offB0 = (wc * 64 + l15) * 128 + c0 * 16;

  f32x4 acc[4][4] = {};

  const char* Ag = (const char*)Xh + (size_t)mb * 12 * 16384;
  const char* Bg = (const char*)Wh + (size_t)nb * 12 * 16384;

  char* a_dst = As + (t & 192) * 16;
  char* b_dst = Bs + (t & 192) * 16;

  for (int ks = 0; ks < 12; ++ks) {
    __syncthreads();
    const char* a_src = Ag + ks * 16384 + t * 16;
    const char* b_src = Bg + ks * 16384 + t * 16;
#pragma unroll
    for (int r = 0; r < 4; ++r) {
      gll16(a_dst + r * 4096, a_src + r * 4096);
      gll16(b_dst + r * 4096, b_src + r * 4096);
    }
    asm volatile("s_waitcnt vmcnt(0)" ::: "memory");
    __syncthreads();
#pragma unroll
    for (int kk = 0; kk < 2; ++kk) {
      f16x8 a[4], b[4];
#pragma unroll
      for (int i = 0; i < 4; ++i)
        a[i] = *reinterpret_cast<const f16x8*>(As + ((offA0 + i * 2048) ^ (kk * 64)));
#pragma unroll
      for (int j = 0; j < 4; ++j)
        b[j] = *reinterpret_cast<const f16x8*>(Bs + ((offB0 + j * 2048) ^ (kk * 64)));
#pragma unroll
      for (int i = 0; i < 4; ++i)
#pragma unroll
        for (int j = 0; j < 4; ++j)
          acc[i][j] = __builtin_amdgcn_mfma_f32_16x16x32_f16(a[i], b[j], acc[i][j], 0, 0, 0);
    }
  }

  // epilogue: + b_enc, non-temporal store, candidate append
  // C/D layout: col = lane&15, row = lq*4 + reg
  const int m0  = mb * 128 + wr * 64 + (lq << 2);
  const int n0g = nb * 128 + wc * 64 + l15;
#pragma unroll
  for (int j = 0; j < 4; ++j) {
    const int col = n0g + j * 16;
    const float bej = be[col];
#pragma unroll
    for (int i = 0; i < 4; ++i) {
      float* dst = &Zp[(size_t)(m0 + i * 16) * D_SAE + col];
#pragma unroll
      for (int rg = 0; rg < 4; ++rg) {
        const float o = acc[i][j][rg] + bej;
        __builtin_nontemporal_store(o, &dst[(size_t)rg * D_SAE]);
        if (o > TCAND) {
          const int row = m0 + i * 16 + rg;
          const int slot = atomicAdd(&cnt[row], 1);
          if (slot < CAP_G)
            cand[(size_t)row * CAP_G + slot] = make_uint2(__float_as_uint(o), (uint32_t)col);
        }
      }
    }
  }
}

// ---------------------------------------------------------------------------
// wave ballot-compacted appends
// ---------------------------------------------------------------------------
__device__ __forceinline__ void wave_append(uint32_t* dv, uint32_t* di, int* counter,
                                            bool pred, uint32_t v, uint32_t idx, int cap)
{
  const unsigned long long m = __ballot(pred ? 1 : 0);
  if (m == 0ull) return;
  const int lane = threadIdx.x & 63;
  const int leader = __ffsll(m) - 1;
  int wbase = 0;
  if (lane == leader) wbase = atomicAdd(counter, __popcll(m));
  wbase = __shfl(wbase, leader);
  if (pred) {
    const int p = wbase + (int)__popcll(m & ((1ull << lane) - 1ull));
    if (p < cap) { dv[p] = v; di[p] = idx; }
  }
}

__device__ __forceinline__ void wave_append64(unsigned long long* dv, int* counter,
                                              bool pred, unsigned long long key, int cap)
{
  const unsigned long long m = __ballot(pred ? 1 : 0);
  if (m == 0ull) return;
  const int lane = threadIdx.x & 63;
  const int leader = __ffsll(m) - 1;
  int wbase = 0;
  if (lane == leader) wbase = atomicAdd(counter, __popcll(m));
  wbase = __shfl(wbase, leader);
  if (pred) {
    const int p = wbase + (int)__popcll(m & ((1ull << lane) - 1ull));
    if (p < cap) dv[p] = key;
  }
}

// exact f32 partial dot over one k-octet using the split arrays
__device__ __forceinline__ float dot_oct(
    const _Float16* __restrict__ Xh, const _Float16* __restrict__ Xl,
    const _Float16* __restrict__ Wh, const _Float16* __restrict__ Wl,
    int r, int c, int go)
{
  const int kb = go >> 3, o = go & 7;
  const size_t xa = ((size_t)((r >> 7) * 12 + kb)) * 8192 +
                    (r & 127) * 64 + ((o ^ (r & 7)) << 3);
  const size_t wa = ((size_t)((c >> 7) * 12 + kb)) * 8192 +
                    (c & 127) * 64 + ((o ^ (c & 7)) << 3);
  const f16x8 xh8 = *reinterpret_cast<const f16x8*>(Xh + xa);
  const f16x8 xl8 = *reinterpret_cast<const f16x8*>(Xl + xa);
  const f16x8 wh8 = *reinterpret_cast<const f16x8*>(Wh + wa);
  const f16x8 wl8 = *reinterpret_cast<const f16x8*>(Wl + wa);
  float p = 0.0f;
#pragma unroll
  for (int e = 0; e < 8; ++e) {
    const float xf = (float)xh8[e] + (float)xl8[e] * (1.0f / 2048.0f);
    const float wf = (float)wh8[e] + (float)wl8[e] * (1.0f / 2048.0f);
    p = fmaf(xf, wf, p);
  }
  return p;
}

// ---------------------------------------------------------------------------
// select_exact: per row — pack candidates as key=(~vbits<<32)|idx, bitonic
// sort ascending (== value desc, idx asc), exact-recompute the boundary band
// in-place, re-sort a 256-wide window covering it, take first 32.
// Rows >= ZROW_SPLIT also zero+scatter their own Zs row inline (scratch-free
// region; overlaps NT writes with other blocks' sort compute).
// ---------------------------------------------------------------------------
__global__ __launch_bounds__(256, 4) void select_exact(
    const float* __restrict__ Zpre, const uint2* __restrict__ cand,
    const int* __restrict__ cnt,
    const _Float16* __restrict__ Xh, const _Float16* __restrict__ Xl,
    const _Float16* __restrict__ Wh, const _Float16* __restrict__ Wl,
    const float* __restrict__ be, const float* __restrict__ Wd,
    const float* __restrict__ bd, uint2* __restrict__ selbuf,
    float* __restrict__ Zs, float* __restrict__ Xr)
{
  __shared__ unsigned long long kv[SORT_N];
  __shared__ int nc_sh, lo_sh, hi_sh;

  const int row  = blockIdx.x;
  const int t    = threadIdx.x;
  const int wave = t >> 6;
  const int lane = t & 63;
  const int n_glob = cnt[row];
  int n;

  const unsigned long long PAD = 0xFFFFFFFF00000000ull;   // v=0, idx=0

  if (n_glob >= KSEL && n_glob <= CAP_G) {
    // fast path: candidates pre-collected by the GEMM epilogue
    n = n_glob;
    const int NSfill = (n <= 256) ? 256 : (n <= 512) ? 512 : SORT_N;
    for (int j = t; j < NSfill; j += 256) {
      unsigned long long key = PAD;
      if (j < n) {
        const uint2 p = cand[(size_t)row * CAP_G + j];
        key = ((unsigned long long)(~p.x) << 32) | p.y;
      }
      kv[j] = key;
    }
    __syncthreads();
  } else {
    // rare fallback: adaptive-threshold full-row rescan of (approx) Zpre
    const float* zrow = Zpre + (size_t)row * D_SAE;
    float T0 = (n_glob > CAP_G) ? 4.0f : 0.5f;
    for (int tries = 0; ; ++tries) {
      for (int j = t; j < SORT_N; j += 256) kv[j] = PAD;
      if (t == 0) nc_sh = 0;
      __syncthreads();
      for (int j4 = t; j4 < D_SAE / 4; j4 += 256) {
        const float4 z4 = *reinterpret_cast<const float4*>(zrow + 4 * j4);
        const float zz[4] = {z4.x, z4.y, z4.z, z4.w};
#pragma unroll
        for (int c = 0; c < 4; ++c) {
          const float v = zz[c] > 0.0f ? zz[c] : 0.0f;
          const unsigned long long key =
              ((unsigned long long)(~__float_as_uint(v)) << 32) | (uint32_t)(4 * j4 + c);
          wave_append64(kv, &nc_sh, v > T0, key, SORT_N);
        }
      }
      __syncthreads();
      n = nc_sh > SORT_N ? SORT_N : nc_sh;
      if ((nc_sh >= KSEL && nc_sh <= SORT_N) || tries >= 9) break;
      T0 = (nc_sh < KSEL) ? ((tries >= 6) ? 0.0f : T0 * 0.25f) : T0 * 2.0f;
      __syncthreads();
    }
    __syncthreads();
  }

  const int NS = (n <= 256) ? 256 : (n <= 512) ? 512 : SORT_N;

  // ---- bitonic sort ascending over kv[0..NS) ----
  for (int k = 2; k <= NS; k <<= 1)
    for (int j2 = k >> 1; j2 > 0; j2 >>= 1) {
      __syncthreads();
      for (int i = t; i < NS; i += 256) {
        const int ixj = i ^ j2;
        if (ixj > i) {
          const unsigned long long a = kv[i], b = kv[ixj];
          const bool up = (i & k) == 0;
          if ((a > b) == up) { kv[i] = b; kv[ixj] = a; }
        }
      }
    }
  __syncthreads();

  const float v32a = __uint_as_float(~(uint32_t)(kv[KSEL - 1] >> 32));

  if (v32a > VGATE) {
    // ---- find band [lo,hi): lo = #(v > v32a+DELTA), hi = #(v >= v32a-DELTA)
    if (t == 0) { lo_sh = 0; hi_sh = 0; }
    __syncthreads();
    int chi = 0, clo = 0;
    for (int j = t; j < n; j += 256) {
      const float v = __uint_as_float(~(uint32_t)(kv[j] >> 32));
      chi += (v > v32a + DELTA) ? 1 : 0;
      clo += (v >= v32a - DELTA) ? 1 : 0;
    }
#pragma unroll
    for (int off = 32; off; off >>= 1) {
      chi += __shfl_xor(chi, off);
      clo += __shfl_xor(clo, off);
    }
    if (lane == 0) { atomicAdd(&lo_sh, chi); atomicAdd(&hi_sh, clo); }
    __syncthreads();
    const int lo = lo_sh;
    int hi = hi_sh;
    if (hi > lo + BCAP) hi = lo + BCAP;

    // ---- exact recompute of band members (one wave per member), in place ----
    for (int mi = lo + wave; mi < hi; mi += 4) {
      const int col = (int)(uint32_t)kv[mi];
      float p = dot_oct(Xh, Xl, Wh, Wl, row, col, lane);
      if (lane < 32) p += dot_oct(Xh, Xl, Wh, Wl, row, col, lane + 64);
#pragma unroll
      for (int off = 32; off; off >>= 1) p += __shfl_xor(p, off);
      if (lane == 0) {
        float e = p + be[col];
        e = e > 0.0f ? e : 0.0f;
        kv[mi] = ((unsigned long long)(~__float_as_uint(e)) << 32) | (uint32_t)col;
      }
    }
    __syncthreads();

    // ---- re-sort the 256-wide window covering the band (lo <= 31,
    // hi-lo <= BCAP < 256): membership of the top-32 is decided inside it ----
    const int wlo = (lo < NS - 256) ? lo : NS - 256;
    for (int k = 2; k <= 256; k <<= 1)
      for (int j2 = k >> 1; j2 > 0; j2 >>= 1) {
        __syncthreads();
        const int i = t;                  // 256 elements, one per thread
        const int ixj = i ^ j2;
        if (ixj > i) {
          const unsigned long long a = kv[wlo + i], b = kv[wlo + ixj];
          const bool up = (i & k) == 0;
          if ((a > b) == up) { kv[wlo + i] = b; kv[wlo + ixj] = a; }
        }
      }
    __syncthreads();
  }

  // ---- emit selection (first 32 of sorted order) ----
  if (t < KSEL) {
    const unsigned long long key = kv[t];
    selbuf[row * KSEL + t] = make_uint2(~(uint32_t)(key >> 32), (uint32_t)key);
  }

  // ---- fused sparse decode: float4 loads over L3-resident Wd ----
  if (t < 192) {
    float4 a4 = *reinterpret_cast<const float4*>(&bd[4 * t]);
#pragma unroll 8
    for (int r = 0; r < KSEL; ++r) {
      const unsigned long long key = kv[r];
      const float v = __uint_as_float(~(uint32_t)(key >> 32));
      const float4 w4 = *reinterpret_cast<const float4*>(
          &Wd[(size_t)(uint32_t)key * D_MODEL + 4 * t]);
      a4.x = fmaf(v, w4.x, a4.x);
      a4.y = fmaf(v, w4.y, a4.y);
      a4.z = fmaf(v, w4.z, a4.z);
      a4.w = fmaf(v, w4.w, a4.w);
    }
    *reinterpret_cast<float4*>(&Xr[(size_t)row * D_MODEL + 4 * t]) = a4;
  }

  // ---- inline zero+scatter of this row's Zs (scratch-free rows only) ----
  if (row >= ZROW_SPLIT) {
    float* zsrow = Zs + (size_t)row * D_SAE;
    const f32x4 z = {0.0f, 0.0f, 0.0f, 0.0f};
    f32x4* p4 = reinterpret_cast<f32x4*>(zsrow);
#pragma unroll
    for (int r = 0; r < 24; ++r)
      __builtin_nontemporal_store(z, p4 + r * 256 + t);
    __syncthreads();                       // drains vmem before scatter
    if (t < KSEL) {
      const unsigned long long key = kv[t];
      const uint32_t vbits = ~(uint32_t)(key >> 32);
      if (vbits) zsrow[(uint32_t)key] = __uint_as_float(vbits);
    }
  }
}

// ---------------------------------------------------------------------------
// ws-too-small fallback: exact 3-pass gemm (R7-proven) + monolithic topk
// ---------------------------------------------------------------------------
__global__ __launch_bounds__(256, 3) void gemm_split3(
    const _Float16* __restrict__ Xh, const _Float16* __restrict__ Xl,
    const _Float16* __restrict__ Wh, const _Float16* __restrict__ Wl,
    const float* __restrict__ be, float* __restrict__ Zp)
{
  __shared__ char lds[32768];
  char* As = lds;
  char* Bs = lds + 16384;

  const int bid = blockIdx.x;
  const int wg  = (bid & 7) * 768 + (bid >> 3);
  const int mb  = wg & 31;
  const int nb  = wg >> 5;

  const int t = threadIdx.x, lane = t & 63, w = t >> 6;
  const int wr = w >> 1, wc = w & 1;
  const int l15 = lane & 15, lq = lane >> 4;
  const int c0 = lq ^ (lane & 7);
  const int offA0 = (wr * 64 + l15) * 128 + c0 * 16;
  const int offB0 = (wc * 64 + l15) * 128 + c0 * 16;

  f32x4 acc[4][4] = {};

  const size_t tA = (size_t)mb * 12 * 16384;
  const size_t tB = (size_t)nb * 12 * 16384;

  char* a_dst = As + (t & 192) * 16;
  char* b_dst = Bs + (t & 192) * 16;

  auto run_pass = [&](const char* Ag, const char* Bg) {
    for (int ks = 0; ks < 12; ++ks) {
      __syncthreads();
      const char* a_src = Ag + ks * 16384 + t * 16;
      const char* b_src = Bg + ks * 16384 + t * 16;
#pragma unroll
      for (int r = 0; r < 4; ++r) {
        gll16(a_dst + r * 4096, a_src + r * 4096);
        gll16(b_dst + r * 4096, b_src + r * 4096);
      }
      asm volatile("s_waitcnt vmcnt(0)" ::: "memory");
      __syncthreads();
#pragma unroll
      for (int kk = 0; kk < 2; ++kk) {
        f16x8 a[4], b[4];
#pragma unroll
        for (int i = 0; i < 4; ++i)
          a[i] = *reinterpret_cast<const f16x8*>(As + ((offA0 + i * 2048) ^ (kk * 64)));
#pragma unroll
        for (int j = 0; j < 4; ++j)
          b[j] = *reinterpret_cast<const f16x8*>(Bs + ((offB0 + j * 2048) ^ (kk * 64)));
#pragma unroll
        for (int i = 0; i < 4; ++i)
#pragma unroll
          for (int j = 0; j < 4; ++j)
            acc[i][j] = __builtin_amdgcn_mfma_f32_16x16x32_f16(a[i], b[j], acc[i][j], 0, 0, 0);
      }
    }
  };

  run_pass((const char*)Xh + tA, (const char*)Wl + tB);
  run_pass((const char*)Xl + tA, (const char*)Wh + tB);
#pragma unroll
  for (int i = 0; i < 4; ++i)
#pragma unroll
    for (int j = 0; j < 4; ++j) acc[i][j] *= (1.0f / 2048.0f);
  run_pass((const char*)Xh + tA, (const char*)Wh + tB);

  const int m0  = mb * 128 + wr * 64 + (lq << 2);
  const int n0g = nb * 128 + wc * 64 + l15;
#pragma unroll
  for (int j = 0; j < 4; ++j) {
    const int col = n0g + j * 16;
    const float bej = be[col];
#pragma unroll
    for (int i = 0; i < 4; ++i) {
      float* dst = &Zp[(size_t)(m0 + i * 16) * D_SAE + col];
#pragma unroll
      for (int rg = 0; rg < 4; ++rg)
        dst[(size_t)rg * D_SAE] = acc[i][j][rg] + bej;
    }
  }
}

#define CAP 1792
__global__ __launch_bounds__(256, 4) void topk_scatter_decode(
    const float* __restrict__ Zpre, const float* __restrict__ Wd,
    const float* __restrict__ bd, float* __restrict__ Zs, float* __restrict__ Xr)
{
  __shared__ uint32_t cvA[CAP], ciA[CAP], cvB[CAP], ciB[CAP];
  __shared__ uint32_t hist[4][256];
  __shared__ uint32_t bitmap[D_SAE / 32];
  __shared__ uint32_t sel_v[KSEL], sel_i[KSEL];
  __shared__ int nc_sh, sel_sh, new_sh, bin_sh, cg_sh;

  const int row  = blockIdx.x;
  const int t    = threadIdx.x;
  const int wave = t >> 6;
  const float* zrow = Zpre + (size_t)row * D_SAE;

  if (t == 0) nc_sh = 0;
  __syncthreads();
  float T0 = 2.0f;
  int n_cur = 0;
  for (int tries = 0; ; ++tries) {
    for (int j4 = t; j4 < D_SAE / 4; j4 += 256) {
      const float4 z4 = *reinterpret_cast<const float4*>(zrow + 4 * j4);
      const float zz[4] = {z4.x, z4.y, z4.z, z4.w};
#pragma unroll
      for (int c = 0; c < 4; ++c) {
        const float v = zz[c] > 0.0f ? zz[c] : 0.0f;
        wave_append(cvA, ciA, &nc_sh, v > T0, __float_as_uint(v),
                    (uint32_t)(4 * j4 + c), CAP);
      }
    }
    __syncthreads();
    n_cur = nc_sh;
    if ((n_cur >= KSEL && n_cur <= CAP) || tries >= 9) break;
    __syncthreads();
    if (t == 0) nc_sh = 0;
    T0 = (n_cur < KSEL) ? ((tries >= 6) ? 0.0f : T0 * 0.25f) : T0 * 2.0f;
    __syncthreads();
  }
  if (n_cur > CAP) n_cur = CAP;

  if (t == 0) sel_sh = 0;
  __syncthreads();
  uint32_t* cv = cvA; uint32_t* ci = ciA;
  uint32_t* nv = cvB; uint32_t* ni = ciB;
  int need = KSEL;

  for (int L = 3; L >= 0; --L) {
    if (need <= 0 || n_cur <= 0) break;
    hist[0][t] = 0; hist[1][t] = 0; hist[2][t] = 0; hist[3][t] = 0;
    __syncthreads();
    for (int j = t; j < n_cur; j += 256)
      atomicAdd(&hist[wave][(cv[j] >> (L * 8)) & 255u], 1u);
    __syncthreads();
    if (t == 0) {
      int cum = 0, b = 255;
      for (; b >= 0; --b) {
        const int h = (int)(hist[0][b] + hist[1][b] + hist[2][b] + hist[3][b]);
        if (cum + h >= need) break;
        cum += h;
      }
      bin_sh = b; cg_sh = cum; new_sh = 0;
    }
    __syncthreads();
    const int B = bin_sh;
    const int rounds = (n_cur + 255) / 256;
    for (int rd = 0; rd < rounds; ++rd) {
      const int j = rd * 256 + t;
      const bool valid = j < n_cur;
      const uint32_t v  = valid ? cv[j] : 0u;
      const uint32_t ix = valid ? ci[j] : 0u;
      const int by = valid ? (int)((v >> (L * 8)) & 255u) : -1;
      wave_append(sel_v, sel_i, &sel_sh, valid && by > B, v, ix, KSEL);
      wave_append(nv, ni, &new_sh, valid && by == B, v, ix, CAP);
    }
    __syncthreads();
    need -= cg_sh;
    n_cur = new_sh < CAP ? new_sh : CAP;
    uint32_t* tv = cv; cv = nv; nv = tv;
    uint32_t* ti = ci; ci = ni; ni = ti;
  }

  if (t == 0) {
    int s = sel_sh;
    const int take = (need < n_cur ? need : n_cur);
    uint32_t last = 0u; bool first = true;
    for (int r = 0; r < take; ++r) {
      uint32_t best = 0xFFFFFFFFu, bv = 0u;
      for (int j = 0; j < n_cur; ++j) {
        const uint32_t ix = ci[j];
        if ((first || ix > last) && ix < best) { best = ix; bv = cv[j]; }
      }
      sel_v[s] = bv; sel_i[s] = best; ++s; last = best; first = false;
    }
    for (; s < KSEL; ++s) { sel_v[s] = 0u; sel_i[s] = 0u; }
  }
  __syncthreads();

  bitmap[t] = 0u; bitmap[t + 256] = 0u; bitmap[t + 512] = 0u;
  __syncthreads();
  if (t < KSEL && sel_v[t] != 0u)
    atomicOr(&bitmap[sel_i[t] >> 5], 1u << (sel_i[t] & 31));
  __syncthreads();

  float* zsrow = Zs + (size_t)row * D_SAE;
  for (int j4 = t; j4 < D_SAE / 4; j4 += 256) {
    const float4 z4 = *reinterpret_cast<const float4*>(zrow + 4 * j4);
    const float zz[4] = {z4.x, z4.y, z4.z, z4.w};
    const int base = 4 * j4;
    float oo[4];
#pragma unroll
    for (int c = 0; c < 4; ++c) {
      const int idx = base + c;
      const bool sel = (bitmap[idx >> 5] >> (idx & 31)) & 1u;
      const float v = zz[c] > 0.0f ? zz[c] : 0.0f;
      oo[c] = sel ? v : 0.0f;
    }
    float4 o; o.x = oo[0]; o.y = oo[1]; o.z = oo[2]; o.w = oo[3];
    *reinterpret_cast<float4*>(zsrow + base) = o;
  }

  float a0 = bd[t], a1 = bd[t + 256], a2 = bd[t + 512];
#pragma unroll 8
  for (int r = 0; r < KSEL; ++r) {
    const float v = __uint_as_float(sel_v[r]);
    const float* wr = Wd + (size_t)sel_i[r] * D_MODEL;
    a0 = fmaf(v, wr[t], a0);
    a1 = fmaf(v, wr[t + 256], a1);
    a2 = fmaf(v, wr[t + 512], a2);
  }
  float* xrow = Xr + (size_t)row * D_MODEL;
  xrow[t] = a0; xrow[t + 256] = a1; xrow[t + 512] = a2;
}

// ---------------------------------------------------------------------------
extern "C" void kernel_launch(void* const* d_in, const int* in_sizes, int n_in,
                              void* d_out, int out_size, void* d_ws, size_t ws_size,
                              hipStream_t stream) {
  const float* X  = (const float*)d_in[0];
  const float* We = (const float*)d_in[1];
  const float* be = (const float*)d_in[2];
  const float* Wd = (const float*)d_in[3];
  const float* bd = (const float*)d_in[4];

  float* out = (float*)d_out;
  float* Xr  = out;                                   // [4096, 768]
  float* Zs  = out + (size_t)NBATCH * D_MODEL;        // [4096, 24576]
  float* Zp  = Zs + (size_t)NBATCH * D_SAE;           // [4096, 24576]

  // f16 split scratch lives in Zs rows [0, 896) (zeroed after select)
  _Float16* WhP = (_Float16*)Zs;
  _Float16* WlP = WhP + W_ELEMS;
  _Float16* XhP = WlP + W_ELEMS;
  _Float16* XlP = XhP + X_ELEMS;

  split_x<<<dim3(32 * 12), 256, 0, stream>>>(X, XhP, XlP);
  split_w<<<dim3(192 * 12), 256, 0, stream>>>(We, WhP, WlP);

  const size_t ws_needed = NBATCH * sizeof(int) +
                           (size_t)NBATCH * KSEL * sizeof(uint2) +
                           (size_t)NBATCH * CAP_G * sizeof(uint2);
  if (ws_size >= ws_needed) {
    int*   cnt    = (int*)d_ws;
    uint2* selbuf = (uint2*)((char*)d_ws + NBATCH * sizeof(int));
    uint2* cand   = (uint2*)((char*)d_ws + NBATCH * sizeof(int) +
                             (size_t)NBATCH * KSEL * sizeof(uint2));
    zero_cnt<<<dim3(16), 256, 0, stream>>>(cnt);
    gemm_f16<<<dim3(32 * 192), 256, 0, stream>>>(XhP, WhP, be, Zp, cand, cnt);
    select_exact<<<dim3(NBATCH), 256, 0, stream>>>(
        Zp, cand, cnt, XhP, XlP, WhP, WlP, be, Wd, bd, selbuf, Zs, Xr);
    zero_scatter<<<dim3(ZROW_SPLIT), 256, 0, stream>>>(selbuf, Zs);
  } else {
    gemm_split3<<<dim3(32 * 192), 256, 0, stream>>>(XhP, XlP, WhP, WlP, be, Zp);
    topk_scatter_decode<<<dim3(NBATCH), 256, 0, stream>>>(Zp, Wd, bd, Zs, Xr);
  }
}